// Round 10
// baseline (1062.019 us; speedup 1.0000x reference)
//
#include <hip/hip_runtime.h>
#include <hip/hip_bf16.h>
#include <math.h>

#define B_GRAPHS 32
#define NPG 128
#define N_TOTAL 4096
#define M_TOK 4
#define K_SUB 16
#define S_SUB 16384
#define FLATN 262144
#define H 128
#define NH 4
#define DH 32
#define STEPS 16
#define L_GNN 4
#define L_RO 2
#define EDGE_DIM 5
#define E_GLOB 32768
#define E_INTRA 524288
#define FFN 512
#define LDW 136

typedef __hip_bfloat16 bf16;
typedef __attribute__((ext_vector_type(8))) short s16x8;
typedef __attribute__((ext_vector_type(4))) float f32x4;

__device__ __forceinline__ float b2f(bf16 v) { return __bfloat162float(v); }
__device__ __forceinline__ bf16 f2b(float v) { return __float2bfloat16(v); }
__device__ __forceinline__ unsigned short f2bu(float v) {
    bf16 b = __float2bfloat16(v);
    return *(unsigned short*)&b;
}
__device__ __forceinline__ float rb2f(short u) {
    return __uint_as_float(((unsigned int)(unsigned short)u) << 16);
}

// ------------------------------------------------------------- utility ---

__global__ void k_zero4(float4* __restrict__ p, int n4) {
    int i = blockIdx.x * 256 + threadIdx.x;
    if (i < n4) p[i] = make_float4(0.f, 0.f, 0.f, 0.f);
}

__global__ void k_zeroi(int* __restrict__ p, int n) {
    int i = blockIdx.x * 256 + threadIdx.x;
    if (i < n) p[i] = 0;
}

// ------------------------------------------------------------ CSR build --

__global__ void k_hist_edge(const int* __restrict__ iei, int* __restrict__ deg) {
    int e = blockIdx.x * 256 + threadIdx.x;
    if (e < E_INTRA) atomicAdd(&deg[iei[E_INTRA + e]], 1);
}

__global__ void k_hist_pool(const int* __restrict__ nid, int* __restrict__ degN) {
    int f = blockIdx.x * 256 + threadIdx.x;
    if (f < FLATN) atomicAdd(&degN[min(max(nid[f], 0), N_TOTAL - 1)], 1);
}

__global__ __launch_bounds__(256) void k_scan_blk(const int* __restrict__ in,
                                                  int* __restrict__ out,
                                                  int* __restrict__ bsum, int n) {
    __shared__ int s[256];
    int i = blockIdx.x * 256 + threadIdx.x;
    int v = (i < n) ? in[i] : 0;
    s[threadIdx.x] = v;
    __syncthreads();
    #pragma unroll
    for (int off = 1; off < 256; off <<= 1) {
        int t = (threadIdx.x >= off) ? s[threadIdx.x - off] : 0;
        __syncthreads();
        s[threadIdx.x] += t;
        __syncthreads();
    }
    if (i < n) out[i] = s[threadIdx.x] - v;
    if (threadIdx.x == 255) bsum[blockIdx.x] = s[255];
}

__global__ __launch_bounds__(256) void k_scan_top(int* __restrict__ bsum, int nb) {
    __shared__ int s[256];
    int base = threadIdx.x * 4;
    int v[4]; int loc = 0;
    #pragma unroll
    for (int j = 0; j < 4; ++j) {
        v[j] = (base + j < nb) ? bsum[base + j] : 0;
        loc += v[j];
    }
    s[threadIdx.x] = loc;
    __syncthreads();
    #pragma unroll
    for (int off = 1; off < 256; off <<= 1) {
        int t = (threadIdx.x >= off) ? s[threadIdx.x - off] : 0;
        __syncthreads();
        s[threadIdx.x] += t;
        __syncthreads();
    }
    int run = s[threadIdx.x] - loc;
    #pragma unroll
    for (int j = 0; j < 4; ++j) {
        if (base + j < nb) bsum[base + j] = run;
        run += v[j];
    }
}

__global__ void k_scan_add(int* __restrict__ out, const int* __restrict__ bsum,
                           int* __restrict__ cursor, int n) {
    int i = blockIdx.x * 256 + threadIdx.x;
    if (i < n) {
        int v = out[i] + bsum[i >> 8];
        out[i] = v;
        cursor[i] = v;
    }
}

__global__ void k_scatter_edge(const int* __restrict__ iei, const int* __restrict__ iea,
                               int* __restrict__ cursor, int* __restrict__ payload) {
    int e = blockIdx.x * 256 + threadIdx.x;
    if (e >= E_INTRA) return;
    int d = iei[E_INTRA + e];
    int pos = atomicAdd(&cursor[d], 1);
    payload[pos] = (iei[e] << 3) | iea[e];
}

__global__ void k_scatter_pool(const int* __restrict__ nid, int* __restrict__ cursorN,
                               int* __restrict__ poolidx) {
    int f = blockIdx.x * 256 + threadIdx.x;
    if (f >= FLATN) return;
    int n = min(max(nid[f], 0), N_TOTAL - 1);
    int pos = atomicAdd(&cursorN[n], 1);
    poolidx[pos] = f;
}

// ---------------------------------------------------------------- RWSE ----

__global__ void k_adj(const int* __restrict__ ei, float* __restrict__ T) {
    int e = blockIdx.x * 256 + threadIdx.x;
    if (e >= E_GLOB) return;
    int s = ei[e], d = ei[E_GLOB + e];
    int g = s >> 7;
    atomicAdd(&T[(g * 128 + (s & 127)) * 128 + (d & 127)], 1.0f);
}

__global__ void k_rownorm(float* __restrict__ T) {
    int row = blockIdx.x * 4 + (threadIdx.x >> 6);
    int lane = threadIdx.x & 63;
    float* r = T + (size_t)row * 128;
    float v0 = r[lane], v1 = r[lane + 64];
    float s = v0 + v1;
    #pragma unroll
    for (int off = 32; off > 0; off >>= 1) s += __shfl_down(s, off);
    s = __shfl(s, 0);
    float inv = 1.0f / fmaxf(s, 1.0f);
    r[lane] = v0 * inv;
    r[lane + 64] = v1 * inv;
}

#define RWG 4
#define RWM 32

__global__ __launch_bounds__(256) void k_rwse_mfma(const float* __restrict__ T,
                                                   float* __restrict__ rwse) {
    __shared__ unsigned short P[2][RWM][LDW];
    int g = blockIdx.x / RWG, rb = blockIdx.x % RWG;
    int row0 = rb * RWM;
    int tid = threadIdx.x;
    int w = tid >> 6, l = tid & 63;
    const float* Tg = T + (size_t)g * 16384;

    {
        int r = tid >> 3;
        int c0 = (tid & 7) * 16;
        const float4* src = (const float4*)(Tg + (size_t)(row0 + r) * 128 + c0);
        #pragma unroll
        for (int i = 0; i < 4; ++i) {
            float4 v = src[i];
            ushort4 u;
            u.x = f2bu(v.x); u.y = f2bu(v.y); u.z = f2bu(v.z); u.w = f2bu(v.w);
            *(ushort4*)&P[0][r][c0 + i * 4] = u;
        }
    }
    if (tid < RWM) {
        int gr = row0 + tid;
        rwse[(size_t)(g * 128 + gr) * STEPS] = Tg[(size_t)gr * 128 + gr];
    }

    s16x8 bw[2][4];
    #pragma unroll
    for (int nt = 0; nt < 2; ++nt) {
        int col = w * 32 + nt * 16 + (l & 15);
        #pragma unroll
        for (int kt = 0; kt < 4; ++kt) {
            int k0 = kt * 32 + (l >> 4) * 8;
            #pragma unroll
            for (int j = 0; j < 8; ++j)
                bw[nt][kt][j] = (short)f2bu(Tg[(size_t)(k0 + j) * 128 + col]);
        }
    }
    __syncthreads();

    int cur = 0;
    for (int s = 1; s < STEPS; ++s) {
        f32x4 acc[2][2];
        #pragma unroll
        for (int mt_i = 0; mt_i < 2; ++mt_i)
            #pragma unroll
            for (int nt = 0; nt < 2; ++nt)
                acc[mt_i][nt] = f32x4{0.f, 0.f, 0.f, 0.f};
        #pragma unroll
        for (int kt = 0; kt < 4; ++kt) {
            #pragma unroll
            for (int mt_i = 0; mt_i < 2; ++mt_i) {
                s16x8 a = *(const s16x8*)&P[cur][mt_i * 16 + (l & 15)][kt * 32 + (l >> 4) * 8];
                acc[mt_i][0] = __builtin_amdgcn_mfma_f32_16x16x32_bf16(a, bw[0][kt], acc[mt_i][0], 0, 0, 0);
                acc[mt_i][1] = __builtin_amdgcn_mfma_f32_16x16x32_bf16(a, bw[1][kt], acc[mt_i][1], 0, 0, 0);
            }
        }
        #pragma unroll
        for (int mt_i = 0; mt_i < 2; ++mt_i) {
            #pragma unroll
            for (int nt = 0; nt < 2; ++nt) {
                int col = w * 32 + nt * 16 + (l & 15);
                #pragma unroll
                for (int r = 0; r < 4; ++r) {
                    int lrow = mt_i * 16 + (l >> 4) * 4 + r;
                    P[cur ^ 1][lrow][col] = f2bu(acc[mt_i][nt][r]);
                    if (row0 + lrow == col)
                        rwse[(size_t)(g * 128 + col) * STEPS + s] = acc[mt_i][nt][r];
                }
            }
        }
        __syncthreads();
        cur ^= 1;
    }
}

__global__ void k_rwse_head(const float* __restrict__ rwse, const float* __restrict__ rwse_W,
                            const float* __restrict__ rwse_b, const float* __restrict__ atom_emb,
                            const int* __restrict__ x_ids, float* __restrict__ base) {
    int idx = blockIdx.x * 256 + threadIdx.x;
    int n = idx >> 7, c = idx & 127;
    const float* r = rwse + (size_t)n * STEPS;
    float acc = rwse_b[c];
    #pragma unroll
    for (int s = 0; s < STEPS; ++s) acc += r[s] * rwse_W[s * H + c];
    acc = fmaxf(acc, 0.f);
    base[idx] = acc + atom_emb[x_ids[n] * H + c];
}

__global__ void k_hinit(const float* __restrict__ base, const int* __restrict__ node_ids,
                        bf16* __restrict__ h) {
    int idx = blockIdx.x * 256 + threadIdx.x;
    int f = idx >> 7, c = idx & 127;
    int nidv = node_ids[f];
    int n = min(max(nidv, 0), N_TOTAL - 1);
    float v = base[n * H + c];
    if (nidv < 0) v = 0.f;
    h[idx] = f2b(v);
}

// ---------------------------------------------------------------- GNN -----

// gpool[n] = sum of h rows mapping to n; also zeroes gagg (same index space)
// ahead of k_gagg's atomics (stream-ordered).
__global__ void k_pool_csr(const bf16* __restrict__ h, const int* __restrict__ rpN,
                           const int* __restrict__ degN, const int* __restrict__ poolidx,
                           float* __restrict__ gpool, float* __restrict__ gagg) {
    int idx = blockIdx.x * 256 + threadIdx.x;
    int n = idx >> 7, c = idx & 127;
    gagg[idx] = 0.f;
    float acc = 0.f;
    int beg = rpN[n], end = beg + degN[n];
    for (int j = beg; j < end; ++j) {
        int f = poolidx[j];
        acc += b2f(h[(size_t)f * H + c]);
    }
    gpool[idx] = acc;
}

__global__ void k_gagg(const float* __restrict__ gpool, const float* __restrict__ bond_emb,
                       const int* __restrict__ ei, const int* __restrict__ ea_ids,
                       float* __restrict__ gagg) {
    int idx = blockIdx.x * 256 + threadIdx.x;
    int e = idx >> 7, c = idx & 127;
    int s = ei[e], d = ei[E_GLOB + e];
    float v = fmaxf(gpool[s * H + c] + bond_emb[(ea_ids[e] - 1) * H + c], 0.f);
    atomicAdd(&gagg[d * H + c], v);
}

// z[f] = h[f] + gagg[nid[f]] + sum_e relu(h[src_e] + ea_e), written bf16.
// High-TLP design: many independent (f, c8) work items.
__global__ void k_aggz(const bf16* __restrict__ h, const float* __restrict__ gagg,
                       const float* __restrict__ bond_emb, const int* __restrict__ node_ids,
                       const int* __restrict__ rp, const int* __restrict__ deg,
                       const int* __restrict__ payload, bf16* __restrict__ z) {
    int idx = blockIdx.x * 256 + threadIdx.x;
    int f = idx >> 4, c8 = (idx & 15) << 3;
    int n = min(max(node_ids[f], 0), N_TOTAL - 1);
    float acc[8];
    s16x8 hv = *(const s16x8*)(h + (size_t)f * H + c8);
    const float* gg = gagg + (size_t)n * H + c8;
    #pragma unroll
    for (int j = 0; j < 8; ++j) acc[j] = rb2f(hv[j]) + gg[j];
    int beg = rp[f], end = beg + deg[f];
    for (int e = beg; e < end; ++e) {
        int p = payload[e];
        int src = p >> 3, ea = (p & 7) - 1;
        s16x8 hs = *(const s16x8*)(h + (size_t)src * H + c8);
        const float* be = bond_emb + ea * H + c8;
        #pragma unroll
        for (int j = 0; j < 8; ++j) acc[j] += fmaxf(rb2f(hs[j]) + be[j], 0.f);
    }
    s16x8 o;
    #pragma unroll
    for (int j = 0; j < 8; ++j) o[j] = (short)f2bu(acc[j]);
    *(s16x8*)(z + (size_t)f * H + c8) = o;
}

// Fused GINE MLP: h = (h + W2@relu(W1@z + b1) + b2) * valid, bf16 MFMA.
// Single 35 KB LDS work buffer (z tile -> mid -> out bounce) for 4 blocks/CU,
// with BOTH W1/W2 fragments loaded upfront (overlapping staging latency) —
// isolates round-8's confound (its regression came from the deferred W2
// load serialized between the GEMMs, not from the single buffer).
__global__ __launch_bounds__(256) void k_mlp_fused(
    const float* __restrict__ W1, const float* __restrict__ b1,
    const float* __restrict__ W2, const float* __restrict__ b2,
    const bf16* __restrict__ z, const int* __restrict__ node_ids,
    bf16* __restrict__ h) {
    __shared__ unsigned short work[128][LDW];
    __shared__ float validf[128];

    int tid = threadIdx.x;
    int w = tid >> 6;
    int l = tid & 63;
    int brow0 = blockIdx.x * 128;

    // --- stage z tile (bf16 copy) + valid flags ---
    {
        int r = tid >> 1, c0 = (tid & 1) * 64;
        const s16x8* zr = (const s16x8*)(z + (size_t)(brow0 + r) * H + c0);
        #pragma unroll
        for (int i = 0; i < 8; ++i)
            *(s16x8*)&work[r][c0 + i * 8] = zr[i];
        if (tid < 128) validf[tid] = (node_ids[brow0 + tid] >= 0) ? 1.f : 0.f;
    }

    // --- W1/W2 fragments upfront (overlap with staging latency) ---
    s16x8 bw1[2][4], bw2[2][4];
    float b1c[2], b2c[2];
    #pragma unroll
    for (int nt = 0; nt < 2; ++nt) {
        int col = w * 32 + nt * 16 + (l & 15);
        b1c[nt] = b1[col];
        b2c[nt] = b2[col];
        #pragma unroll
        for (int kt = 0; kt < 4; ++kt) {
            int k0 = kt * 32 + (l >> 4) * 8;
            #pragma unroll
            for (int j = 0; j < 8; ++j) {
                bw1[nt][kt][j] = (short)f2bu(W1[(size_t)(k0 + j) * H + col]);
                bw2[nt][kt][j] = (short)f2bu(W2[(size_t)(k0 + j) * H + col]);
            }
        }
    }
    __syncthreads();

    // --- GEMM1: acc = z @ W1 (reads work) ---
    f32x4 acc[8][2];
    #pragma unroll
    for (int mt_i = 0; mt_i < 8; ++mt_i)
        #pragma unroll
        for (int nt = 0; nt < 2; ++nt)
            acc[mt_i][nt] = f32x4{0.f, 0.f, 0.f, 0.f};
    #pragma unroll
    for (int kt = 0; kt < 4; ++kt) {
        #pragma unroll
        for (int mt_i = 0; mt_i < 8; ++mt_i) {
            s16x8 a = *(const s16x8*)&work[mt_i * 16 + (l & 15)][kt * 32 + (l >> 4) * 8];
            acc[mt_i][0] = __builtin_amdgcn_mfma_f32_16x16x32_bf16(a, bw1[0][kt], acc[mt_i][0], 0, 0, 0);
            acc[mt_i][1] = __builtin_amdgcn_mfma_f32_16x16x32_bf16(a, bw1[1][kt], acc[mt_i][1], 0, 0, 0);
        }
    }
    __syncthreads();   // all z reads done; work reusable for mid

    // --- write mid = relu(acc + b1) into the same buffer ---
    #pragma unroll
    for (int mt_i = 0; mt_i < 8; ++mt_i) {
        #pragma unroll
        for (int nt = 0; nt < 2; ++nt) {
            int col = w * 32 + nt * 16 + (l & 15);
            #pragma unroll
            for (int r = 0; r < 4; ++r) {
                int row = mt_i * 16 + (l >> 4) * 4 + r;
                work[row][col] = f2bu(fmaxf(acc[mt_i][nt][r] + b1c[nt], 0.f));
            }
        }
    }
    __syncthreads();   // mid writes visible

    // --- GEMM2: out = mid @ W2 ---
    #pragma unroll
    for (int mt_i = 0; mt_i < 8; ++mt_i)
        #pragma unroll
        for (int nt = 0; nt < 2; ++nt)
            acc[mt_i][nt] = f32x4{0.f, 0.f, 0.f, 0.f};
    #pragma unroll
    for (int kt = 0; kt < 4; ++kt) {
        #pragma unroll
        for (int mt_i = 0; mt_i < 8; ++mt_i) {
            s16x8 a = *(const s16x8*)&work[mt_i * 16 + (l & 15)][kt * 32 + (l >> 4) * 8];
            acc[mt_i][0] = __builtin_amdgcn_mfma_f32_16x16x32_bf16(a, bw2[0][kt], acc[mt_i][0], 0, 0, 0);
            acc[mt_i][1] = __builtin_amdgcn_mfma_f32_16x16x32_bf16(a, bw2[1][kt], acc[mt_i][1], 0, 0, 0);
        }
    }
    __syncthreads();   // all mid reads done; work reusable for output bounce

    // --- epilogue: bounce out+b2 through work, then coalesced residual RMW ---
    #pragma unroll
    for (int mt_i = 0; mt_i < 8; ++mt_i) {
        #pragma unroll
        for (int nt = 0; nt < 2; ++nt) {
            int col = w * 32 + nt * 16 + (l & 15);
            #pragma unroll
            for (int r = 0; r < 4; ++r) {
                int row = mt_i * 16 + (l >> 4) * 4 + r;
                work[row][col] = f2bu(acc[mt_i][nt][r] + b2c[nt]);
            }
        }
    }
    __syncthreads();
    {
        int r = tid >> 1, c0 = (tid & 1) * 64;
        float vf = validf[r];
        s16x8* hr = (s16x8*)(h + (size_t)(brow0 + r) * H + c0);
        #pragma unroll
        for (int i = 0; i < 8; ++i) {
            s16x8 hv = hr[i];
            s16x8 ov = *(const s16x8*)&work[r][c0 + i * 8];
            s16x8 o;
            #pragma unroll
            for (int j = 0; j < 8; ++j)
                o[j] = (short)f2bu((rb2f(hv[j]) + rb2f(ov[j])) * vf);
            hr[i] = o;
        }
    }
}

// ------------------------------------------------------------- Readout ---

__global__ void k_tok(const bf16* __restrict__ h, float* __restrict__ htok) {
    int idx = blockIdx.x * 256 + threadIdx.x;
    int s = idx >> 7, c = idx & 127;
    htok[idx] = b2f(h[(size_t)s * K_SUB * H + c]);
}

// K1: LN1 + QKV(MFMA) + attention + Wo(MFMA) + residual.
#define ROQ_STR 408

__global__ __launch_bounds__(256) void k_ro_attn(
    float* __restrict__ htok,
    const float* __restrict__ g1, const float* __restrict__ b1,
    const float* __restrict__ Wqkv, const float* __restrict__ bqkv,
    const float* __restrict__ Wo, const float* __restrict__ bo,
    const float* __restrict__ log_probs, const float* __restrict__ alpha_p) {
    __shared__ unsigned short xn[64][LDW];
    __shared__ unsigned short qkv[64][ROQ_STR];
    __shared__ float lpv[64];
    int tid = threadIdx.x;
    int w = tid >> 6, l = tid & 63;
    int g0 = blockIdx.x * 64;
    float alpha = alpha_p[0];

    {
        int t = tid >> 2, q = tid & 3;
        const float4* xr = (const float4*)(htok + (size_t)(g0 + t) * H + q * 32);
        float x[32]; float s = 0.f, ss = 0.f;
        #pragma unroll
        for (int i = 0; i < 8; ++i) {
            float4 v = xr[i];
            x[i * 4 + 0] = v.x; x[i * 4 + 1] = v.y; x[i * 4 + 2] = v.z; x[i * 4 + 3] = v.w;
            s += v.x + v.y + v.z + v.w;
            ss += v.x * v.x + v.y * v.y + v.z * v.z + v.w * v.w;
        }
        s += __shfl_xor(s, 1); ss += __shfl_xor(ss, 1);
        s += __shfl_xor(s, 2); ss += __shfl_xor(ss, 2);
        float mu = s * (1.f / 128.f);
        float var = ss * (1.f / 128.f) - mu * mu;
        float inv = rsqrtf(var + 1e-5f);
        #pragma unroll
        for (int i = 0; i < 32; ++i) {
            int c = q * 32 + i;
            xn[t][c] = f2bu((x[i] - mu) * inv * g1[c] + b1[c]);
        }
        if (tid < 64) {
            float lp = log_probs[g0 + tid];
            lpv[tid] = isfinite(lp) ? lp : 0.f;
        }
    }
    __syncthreads();

    s16x8 a[4][4];
    #pragma unroll
    for (int mt_i = 0; mt_i < 4; ++mt_i)
        #pragma unroll
        for (int kt = 0; kt < 4; ++kt)
            a[mt_i][kt] = *(const s16x8*)&xn[mt_i * 16 + (l & 15)][kt * 32 + (l >> 4) * 8];

    #pragma unroll
    for (int nt = 0; nt < 6; ++nt) {
        int col = w * 96 + nt * 16 + (l & 15);
        s16x8 bw[4];
        #pragma unroll
        for (int kt = 0; kt < 4; ++kt) {
            int k0 = kt * 32 + (l >> 4) * 8;
            #pragma unroll
            for (int j = 0; j < 8; ++j)
                bw[kt][j] = (short)f2bu(Wqkv[(size_t)(k0 + j) * 384 + col]);
        }
        f32x4 acc[4];
        #pragma unroll
        for (int mt_i = 0; mt_i < 4; ++mt_i) acc[mt_i] = f32x4{0.f, 0.f, 0.f, 0.f};
        #pragma unroll
        for (int kt = 0; kt < 4; ++kt)
            #pragma unroll
            for (int mt_i = 0; mt_i < 4; ++mt_i)
                acc[mt_i] = __builtin_amdgcn_mfma_f32_16x16x32_bf16(a[mt_i][kt], bw[kt], acc[mt_i], 0, 0, 0);
        float bb = bqkv[col];
        #pragma unroll
        for (int mt_i = 0; mt_i < 4; ++mt_i)
            #pragma unroll
            for (int r = 0; r < 4; ++r)
                qkv[mt_i * 16 + (l >> 4) * 4 + r][col] = f2bu(acc[mt_i][r] + bb);
    }
    __syncthreads();

    {
        int node = tid >> 4, hh = (tid >> 2) & 3, ii = tid & 3;
        int t0 = node * 4;
        float qv[32];
        #pragma unroll
        for (int j4 = 0; j4 < 4; ++j4) {
            s16x8 v = *(const s16x8*)&qkv[t0 + ii][hh * 32 + j4 * 8];
            #pragma unroll
            for (int j = 0; j < 8; ++j) qv[j4 * 8 + j] = rb2f(v[j]);
        }
        float sc[4];
        #pragma unroll
        for (int jj = 0; jj < 4; ++jj) {
            float d = 0.f;
            #pragma unroll
            for (int j4 = 0; j4 < 4; ++j4) {
                s16x8 kv = *(const s16x8*)&qkv[t0 + jj][128 + hh * 32 + j4 * 8];
                #pragma unroll
                for (int j = 0; j < 8; ++j) d += qv[j4 * 8 + j] * rb2f(kv[j]);
            }
            sc[jj] = d * 0.17677669529663689f + alpha * lpv[t0 + jj];
        }
        float mx = fmaxf(fmaxf(sc[0], sc[1]), fmaxf(sc[2], sc[3]));
        float p[4]; float se = 0.f;
        #pragma unroll
        for (int jj = 0; jj < 4; ++jj) { p[jj] = expf(sc[jj] - mx); se += p[jj]; }
        float inv = 1.f / se;
        #pragma unroll
        for (int jj = 0; jj < 4; ++jj) p[jj] *= inv;
        float ov[32];
        #pragma unroll
        for (int i = 0; i < 32; ++i) ov[i] = 0.f;
        #pragma unroll
        for (int jj = 0; jj < 4; ++jj) {
            #pragma unroll
            for (int j4 = 0; j4 < 4; ++j4) {
                s16x8 vv = *(const s16x8*)&qkv[t0 + jj][256 + hh * 32 + j4 * 8];
                #pragma unroll
                for (int j = 0; j < 8; ++j) ov[j4 * 8 + j] += p[jj] * rb2f(vv[j]);
            }
        }
        __syncthreads();
        #pragma unroll
        for (int j4 = 0; j4 < 4; ++j4) {
            s16x8 o8;
            #pragma unroll
            for (int j = 0; j < 8; ++j) o8[j] = (short)f2bu(ov[j4 * 8 + j]);
            *(s16x8*)&xn[t0 + ii][hh * 32 + j4 * 8] = o8;
        }
    }
    __syncthreads();

    s16x8 ao[4][4];
    #pragma unroll
    for (int mt_i = 0; mt_i < 4; ++mt_i)
        #pragma unroll
        for (int kt = 0; kt < 4; ++kt)
            ao[mt_i][kt] = *(const s16x8*)&xn[mt_i * 16 + (l & 15)][kt * 32 + (l >> 4) * 8];
    #pragma unroll
    for (int nt = 0; nt < 2; ++nt) {
        int col = w * 32 + nt * 16 + (l & 15);
        s16x8 bw[4];
        #pragma unroll
        for (int kt = 0; kt < 4; ++kt) {
            int k0 = kt * 32 + (l >> 4) * 8;
            #pragma unroll
            for (int j = 0; j < 8; ++j)
                bw[kt][j] = (short)f2bu(Wo[(size_t)(k0 + j) * H + col]);
        }
        f32x4 acc[4];
        #pragma unroll
        for (int mt_i = 0; mt_i < 4; ++mt_i) acc[mt_i] = f32x4{0.f, 0.f, 0.f, 0.f};
        #pragma unroll
        for (int kt = 0; kt < 4; ++kt)
            #pragma unroll
            for (int mt_i = 0; mt_i < 4; ++mt_i)
                acc[mt_i] = __builtin_amdgcn_mfma_f32_16x16x32_bf16(ao[mt_i][kt], bw[kt], acc[mt_i], 0, 0, 0);
        float bb = bo[col];
        #pragma unroll
        for (int mt_i = 0; mt_i < 4; ++mt_i)
            #pragma unroll
            for (int r = 0; r < 4; ++r) {
                int row = mt_i * 16 + (l >> 4) * 4 + r;
                size_t gg = (size_t)(g0 + row) * H + col;
                htok[gg] += acc[mt_i][r] + bb;
            }
    }
}

// K2: LN2 + FFN1(gelu) + FFN2 (K-blocked) + residual.
__global__ __launch_bounds__(256) void k_ro_ffn(
    float* __restrict__ htok,
    const float* __restrict__ g2, const float* __restrict__ b2,
    const float* __restrict__ Wf1, const float* __restrict__ bf1,
    const float* __restrict__ Wf2, const float* __restrict__ bf2) {
    __shared__ unsigned short xb[64][LDW];
    int tid = threadIdx.x;
    int w = tid >> 6, l = tid & 63;
    int g0 = blockIdx.x * 64;

    {
        int t = tid >> 2, q = tid & 3;
        const float4* xr = (const float4*)(htok + (size_t)(g0 + t) * H + q * 32);
        float x[32]; float s = 0.f, ss = 0.f;
        #pragma unroll
        for (int i = 0; i < 8; ++i) {
            float4 v = xr[i];
            x[i * 4 + 0] = v.x; x[i * 4 + 1] = v.y; x[i * 4 + 2] = v.z; x[i * 4 + 3] = v.w;
            s += v.x + v.y + v.z + v.w;
            ss += v.x * v.x + v.y * v.y + v.z * v.z + v.w * v.w;
        }
        s += __shfl_xor(s, 1); ss += __shfl_xor(ss, 1);
        s += __shfl_xor(s, 2); ss += __shfl_xor(ss, 2);
        float mu = s * (1.f / 128.f);
        float var = ss * (1.f / 128.f) - mu * mu;
        float inv = rsqrtf(var + 1e-5f);
        #pragma unroll
        for (int i = 0; i < 32; ++i) {
            int c = q * 32 + i;
            xb[t][c] = f2bu((x[i] - mu) * inv * g2[c] + b2[c]);
        }
    }
    __syncthreads();

    s16x8 a2[4][4];
    #pragma unroll
    for (int mt_i = 0; mt_i < 4; ++mt_i)
        #pragma unroll
        for (int kt = 0; kt < 4; ++kt)
            a2[mt_i][kt] = *(const s16x8*)&xb[mt_i * 16 + (l & 15)][kt * 32 + (l >> 4) * 8];
    __syncthreads();

    f32x4 acc2[4][2];
    #pragma unroll
    for (int mt_i = 0; mt_i < 4; ++mt_i)
        #pragma unroll
        for (int nt = 0; nt < 2; ++nt)
            acc2[mt_i][nt] = f32x4{0.f, 0.f, 0.f, 0.f};

    #pragma unroll
    for (int cc = 0; cc < 4; ++cc) {
        #pragma unroll
        for (int nt = 0; nt < 2; ++nt) {
            int colf = cc * 128 + w * 32 + nt * 16 + (l & 15);
            s16x8 bw[4];
            #pragma unroll
            for (int kt = 0; kt < 4; ++kt) {
                int k0 = kt * 32 + (l >> 4) * 8;
                #pragma unroll
                for (int j = 0; j < 8; ++j)
                    bw[kt][j] = (short)f2bu(Wf1[(size_t)(k0 + j) * FFN + colf]);
            }
            f32x4 accm[4];
            #pragma unroll
            for (int mt_i = 0; mt_i < 4; ++mt_i) accm[mt_i] = f32x4{0.f, 0.f, 0.f, 0.f};
            #pragma unroll
            for (int kt = 0; kt < 4; ++kt)
                #pragma unroll
                for (int mt_i = 0; mt_i < 4; ++mt_i)
                    accm[mt_i] = __builtin_amdgcn_mfma_f32_16x16x32_bf16(a2[mt_i][kt], bw[kt], accm[mt_i], 0, 0, 0);
            float bb = bf1[colf];
            int colw = w * 32 + nt * 16 + (l & 15);
            #pragma unroll
            for (int mt_i = 0; mt_i < 4; ++mt_i)
                #pragma unroll
                for (int r = 0; r < 4; ++r) {
                    float v = accm[mt_i][r] + bb;
                    v = v * 0.5f * (1.f + erff(v * 0.70710678118654752f));
                    xb[mt_i * 16 + (l >> 4) * 4 + r][colw] = f2bu(v);
                }
        }
        __syncthreads();
        s16x8 am[4][4];
        #pragma unroll
        for (int mt_i = 0; mt_i < 4; ++mt_i)
            #pragma unroll
            for (int kt = 0; kt < 4; ++kt)
                am[mt_i][kt] = *(const s16x8*)&xb[mt_i * 16 + (l & 15)][kt * 32 + (l >> 4) * 8];
        #pragma unroll
        for (int nt = 0; nt < 2; ++nt) {
            int colo = w * 32 + nt * 16 + (l & 15);
            s16x8 bw[4];
            #pragma unroll
            for (int kt = 0; kt < 4; ++kt) {
                int k0 = cc * 128 + kt * 32 + (l >> 4) * 8;
                #pragma unroll
                for (int j = 0; j < 8; ++j)
                    bw[kt][j] = (short)f2bu(Wf2[(size_t)(k0 + j) * H + colo]);
            }
            #pragma unroll
            for (int kt = 0; kt < 4; ++kt)
                #pragma unroll
                for (int mt_i = 0; mt_i < 4; ++mt_i)
                    acc2[mt_i][nt] = __builtin_amdgcn_mfma_f32_16x16x32_bf16(am[mt_i][kt], bw[kt], acc2[mt_i][nt], 0, 0, 0);
        }
        __syncthreads();
    }

    #pragma unroll
    for (int nt = 0; nt < 2; ++nt) {
        int col = w * 32 + nt * 16 + (l & 15);
        float bb = bf2[col];
        #pragma unroll
        for (int mt_i = 0; mt_i < 4; ++mt_i)
            #pragma unroll
            for (int r = 0; r < 4; ++r) {
                int row = mt_i * 16 + (l >> 4) * 4 + r;
                size_t gg = (size_t)(g0 + row) * H + col;
                htok[gg] += acc2[mt_i][nt][r] + bb;
            }
    }
}

__global__ __launch_bounds__(128) void k_nodeemb(const float* __restrict__ htok,
                                                 const float* __restrict__ og,
                                                 const float* __restrict__ ob,
                                                 float* __restrict__ nemb) {
    int n = blockIdx.x, c = threadIdx.x;
    const float* hr = htok + (size_t)n * 4 * H;
    float v = 0.25f * (hr[c] + hr[H + c] + hr[2 * H + c] + hr[3 * H + c]);
    float s = v, ss = v * v;
    #pragma unroll
    for (int m = 1; m < 64; m <<= 1) { s += __shfl_xor(s, m); ss += __shfl_xor(ss, m); }
    __shared__ float red[4];
    if ((threadIdx.x & 63) == 0) {
        red[(threadIdx.x >> 6) * 2] = s;
        red[(threadIdx.x >> 6) * 2 + 1] = ss;
    }
    __syncthreads();
    s = red[0] + red[2];
    ss = red[1] + red[3];
    float mu = s * (1.f / 128.f);
    float var = ss * (1.f / 128.f) - mu * mu;
    float inv = rsqrtf(var + 1e-5f);
    nemb[(size_t)n * H + c] = (v - mu) * inv * og[c] + ob[c];
}

__global__ __launch_bounds__(128) void k_out(const float* __restrict__ nemb,
                                             float* __restrict__ out) {
    int g = blockIdx.x, c = threadIdx.x;
    float acc = 0.f;
    for (int i = 0; i < 128; ++i) acc += nemb[(size_t)(g * 128 + i) * H + c];
    out[g * H + c] = acc;
}

// ------------------------------------------------------------- launch ----

extern "C" void kernel_launch(void* const* d_in, const int* in_sizes, int n_in,
                              void* d_out, int out_size, void* d_ws, size_t ws_size,
                              hipStream_t stream) {
    (void)in_sizes; (void)n_in; (void)out_size;
    const int* edge_index    = (const int*)d_in[0];
    const int* intra_ei      = (const int*)d_in[1];
    const int* edge_attr_ids = (const int*)d_in[2];
    const int* intra_ea_ids  = (const int*)d_in[3];
    const int* node_ids      = (const int*)d_in[4];
    const int* x_ids         = (const int*)d_in[5];
    const float* log_probs   = (const float*)d_in[7];
    const float* atom_emb    = (const float*)d_in[8];
    const float* bond_emb    = (const float*)d_in[9];
    const float* rwse_W      = (const float*)d_in[10];
    const float* rwse_b      = (const float*)d_in[11];
    const float* gnn_W1      = (const float*)d_in[12];
    const float* gnn_b1      = (const float*)d_in[13];
    const float* gnn_W2      = (const float*)d_in[14];
    const float* gnn_b2      = (const float*)d_in[15];
    const float* ro_ln1_g    = (const float*)d_in[16];
    const float* ro_ln1_b    = (const float*)d_in[17];
    const float* ro_Wqkv     = (const float*)d_in[18];
    const float* ro_bqkv     = (const float*)d_in[19];
    const float* ro_Wo       = (const float*)d_in[20];
    const float* ro_bo       = (const float*)d_in[21];
    const float* ro_ln2_g    = (const float*)d_in[22];
    const float* ro_ln2_b    = (const float*)d_in[23];
    const float* ro_Wf1      = (const float*)d_in[24];
    const float* ro_bf1      = (const float*)d_in[25];
    const float* ro_Wf2      = (const float*)d_in[26];
    const float* ro_bf2      = (const float*)d_in[27];
    const float* out_ln_g    = (const float*)d_in[28];
    const float* out_ln_b    = (const float*)d_in[29];
    const float* ht_alpha    = (const float*)d_in[30];

    char* ws = (char*)d_ws;
    size_t off = 0;
    auto alloc = [&](size_t nbytes) {
        char* p = ws + off;
        off += (nbytes + 255) & ~(size_t)255;
        return p;
    };
    float* T       = (float*)alloc((size_t)B_GRAPHS * 128 * 128 * 4);
    float* rwse    = (float*)alloc((size_t)N_TOTAL * STEPS * 4);
    float* base    = (float*)alloc((size_t)N_TOTAL * H * 4);
    float* gbuf    = (float*)alloc((size_t)2 * N_TOTAL * H * 4);
    float* htok    = (float*)alloc((size_t)S_SUB * H * 4);
    float* nemb    = (float*)alloc((size_t)N_TOTAL * H * 4);
    bf16*  z       = (bf16*)alloc((size_t)FLATN * H * 2);
    bf16*  h       = (bf16*)alloc((size_t)FLATN * H * 2);
    int*   deg     = (int*)alloc((size_t)FLATN * 4);
    int*   rp      = (int*)alloc((size_t)FLATN * 4);
    int*   cursor  = (int*)alloc((size_t)FLATN * 4);
    int*   payload = (int*)alloc((size_t)E_INTRA * 4);
    int*   degN    = (int*)alloc((size_t)N_TOTAL * 4);
    int*   rpN     = (int*)alloc((size_t)N_TOTAL * 4);
    int*   cursorN = (int*)alloc((size_t)N_TOTAL * 4);
    int*   poolidx = (int*)alloc((size_t)FLATN * 4);
    int*   bsum    = (int*)alloc(1024 * 4);
    int*   bsumN   = (int*)alloc(16 * 4);
    float* gpool   = gbuf;
    float* gagg    = gbuf + (size_t)N_TOTAL * H;

    if (off > ws_size) return;

    // ---- CSR build ----
    k_zeroi<<<FLATN / 256, 256, 0, stream>>>(deg, FLATN);
    k_zeroi<<<N_TOTAL / 256, 256, 0, stream>>>(degN, N_TOTAL);
    k_hist_edge<<<E_INTRA / 256, 256, 0, stream>>>(intra_ei, deg);
    k_hist_pool<<<FLATN / 256, 256, 0, stream>>>(node_ids, degN);
    k_scan_blk<<<FLATN / 256, 256, 0, stream>>>(deg, rp, bsum, FLATN);
    k_scan_top<<<1, 256, 0, stream>>>(bsum, FLATN / 256);
    k_scan_add<<<FLATN / 256, 256, 0, stream>>>(rp, bsum, cursor, FLATN);
    k_scan_blk<<<N_TOTAL / 256, 256, 0, stream>>>(degN, rpN, bsumN, N_TOTAL);
    k_scan_top<<<1, 256, 0, stream>>>(bsumN, N_TOTAL / 256);
    k_scan_add<<<N_TOTAL / 256, 256, 0, stream>>>(rpN, bsumN, cursorN, N_TOTAL);
    k_scatter_edge<<<E_INTRA / 256, 256, 0, stream>>>(intra_ei, intra_ea_ids, cursor, payload);
    k_scatter_pool<<<FLATN / 256, 256, 0, stream>>>(node_ids, cursorN, poolidx);

    // ---- RWSE ----
    k_zero4<<<(B_GRAPHS * 128 * 128 / 4 + 255) / 256, 256, 0, stream>>>((float4*)T, B_GRAPHS * 128 * 128 / 4);
    k_adj<<<E_GLOB / 256, 256, 0, stream>>>(edge_index, T);
    k_rownorm<<<(B_GRAPHS * 128) / 4, 256, 0, stream>>>(T);
    k_rwse_mfma<<<B_GRAPHS * RWG, 256, 0, stream>>>(T, rwse);
    k_rwse_head<<<(N_TOTAL * H) / 256, 256, 0, stream>>>(rwse, rwse_W, rwse_b, atom_emb, x_ids, base);
    k_hinit<<<(FLATN * H) / 256, 256, 0, stream>>>(base, node_ids, h);

    // ---- GNN layers ----
    for (int l = 0; l < L_GNN; ++l) {
        k_pool_csr<<<(N_TOTAL * H) / 256, 256, 0, stream>>>(h, rpN, degN, poolidx, gpool, gagg);
        k_gagg<<<(E_GLOB * H) / 256, 256, 0, stream>>>(gpool, bond_emb, edge_index, edge_attr_ids, gagg);
        k_aggz<<<(FLATN * 16) / 256, 256, 0, stream>>>(h, gagg, bond_emb, node_ids, rp, deg, payload, z);
        k_mlp_fused<<<FLATN / 128, 256, 0, stream>>>(
            gnn_W1 + (size_t)l * H * H, gnn_b1 + l * H,
            gnn_W2 + (size_t)l * H * H, gnn_b2 + l * H,
            z, node_ids, h);
    }

    // ---- Readout ----
    k_tok<<<(S_SUB * H) / 256, 256, 0, stream>>>(h, htok);
    for (int l = 0; l < L_RO; ++l) {
        k_ro_attn<<<S_SUB * M_TOK / 64 / 4, 256, 0, stream>>>(htok,
            ro_ln1_g + l * H, ro_ln1_b + l * H,
            ro_Wqkv + (size_t)l * H * 3 * H, ro_bqkv + l * 3 * H,
            ro_Wo + (size_t)l * H * H, ro_bo + l * H,
            log_probs, ht_alpha);
        k_ro_ffn<<<S_SUB * M_TOK / 64 / 4, 256, 0, stream>>>(htok,
            ro_ln2_g + l * H, ro_ln2_b + l * H,
            ro_Wf1 + (size_t)l * H * FFN, ro_bf1 + l * FFN,
            ro_Wf2 + (size_t)l * FFN * H, ro_bf2 + l * H);
    }
    k_nodeemb<<<N_TOTAL, 128, 0, stream>>>(htok, out_ln_g, out_ln_b, nemb);
    k_out<<<B_GRAPHS, 128, 0, stream>>>(nemb, (float*)d_out);
}

// Round 11
// 1054.725 us; speedup vs baseline: 1.0069x; 1.0069x over previous
//
#include <hip/hip_runtime.h>
#include <hip/hip_bf16.h>
#include <math.h>

#define B_GRAPHS 32
#define NPG 128
#define N_TOTAL 4096
#define M_TOK 4
#define K_SUB 16
#define S_SUB 16384
#define FLATN 262144
#define H 128
#define NH 4
#define DH 32
#define STEPS 16
#define L_GNN 4
#define L_RO 2
#define EDGE_DIM 5
#define E_GLOB 32768
#define E_INTRA 524288
#define FFN 512
#define LDW 136

typedef __hip_bfloat16 bf16;
typedef __attribute__((ext_vector_type(8))) short s16x8;
typedef __attribute__((ext_vector_type(4))) float f32x4;

__device__ __forceinline__ float b2f(bf16 v) { return __bfloat162float(v); }
__device__ __forceinline__ bf16 f2b(float v) { return __float2bfloat16(v); }
__device__ __forceinline__ unsigned short f2bu(float v) {
    bf16 b = __float2bfloat16(v);
    return *(unsigned short*)&b;
}
__device__ __forceinline__ float rb2f(short u) {
    return __uint_as_float(((unsigned int)(unsigned short)u) << 16);
}

// ------------------------------------------------------------- utility ---

__global__ void k_zero4(float4* __restrict__ p, int n4) {
    int i = blockIdx.x * 256 + threadIdx.x;
    if (i < n4) p[i] = make_float4(0.f, 0.f, 0.f, 0.f);
}

__global__ void k_zeroi(int* __restrict__ p, int n) {
    int i = blockIdx.x * 256 + threadIdx.x;
    if (i < n) p[i] = 0;
}

// ------------------------------------------------------------ CSR build --

__global__ void k_hist_edge(const int* __restrict__ iei, int* __restrict__ deg) {
    int e = blockIdx.x * 256 + threadIdx.x;
    if (e < E_INTRA) atomicAdd(&deg[iei[E_INTRA + e]], 1);
}

__global__ void k_hist_pool(const int* __restrict__ nid, int* __restrict__ degN) {
    int f = blockIdx.x * 256 + threadIdx.x;
    if (f < FLATN) atomicAdd(&degN[min(max(nid[f], 0), N_TOTAL - 1)], 1);
}

__global__ __launch_bounds__(256) void k_scan_blk(const int* __restrict__ in,
                                                  int* __restrict__ out,
                                                  int* __restrict__ bsum, int n) {
    __shared__ int s[256];
    int i = blockIdx.x * 256 + threadIdx.x;
    int v = (i < n) ? in[i] : 0;
    s[threadIdx.x] = v;
    __syncthreads();
    #pragma unroll
    for (int off = 1; off < 256; off <<= 1) {
        int t = (threadIdx.x >= off) ? s[threadIdx.x - off] : 0;
        __syncthreads();
        s[threadIdx.x] += t;
        __syncthreads();
    }
    if (i < n) out[i] = s[threadIdx.x] - v;
    if (threadIdx.x == 255) bsum[blockIdx.x] = s[255];
}

__global__ __launch_bounds__(256) void k_scan_top(int* __restrict__ bsum, int nb) {
    __shared__ int s[256];
    int base = threadIdx.x * 4;
    int v[4]; int loc = 0;
    #pragma unroll
    for (int j = 0; j < 4; ++j) {
        v[j] = (base + j < nb) ? bsum[base + j] : 0;
        loc += v[j];
    }
    s[threadIdx.x] = loc;
    __syncthreads();
    #pragma unroll
    for (int off = 1; off < 256; off <<= 1) {
        int t = (threadIdx.x >= off) ? s[threadIdx.x - off] : 0;
        __syncthreads();
        s[threadIdx.x] += t;
        __syncthreads();
    }
    int run = s[threadIdx.x] - loc;
    #pragma unroll
    for (int j = 0; j < 4; ++j) {
        if (base + j < nb) bsum[base + j] = run;
        run += v[j];
    }
}

__global__ void k_scan_add(int* __restrict__ out, const int* __restrict__ bsum,
                           int* __restrict__ cursor, int n) {
    int i = blockIdx.x * 256 + threadIdx.x;
    if (i < n) {
        int v = out[i] + bsum[i >> 8];
        out[i] = v;
        cursor[i] = v;
    }
}

__global__ void k_scatter_edge(const int* __restrict__ iei, const int* __restrict__ iea,
                               int* __restrict__ cursor, int* __restrict__ payload) {
    int e = blockIdx.x * 256 + threadIdx.x;
    if (e >= E_INTRA) return;
    int d = iei[E_INTRA + e];
    int pos = atomicAdd(&cursor[d], 1);
    payload[pos] = (iei[e] << 3) | iea[e];
}

__global__ void k_scatter_pool(const int* __restrict__ nid, int* __restrict__ cursorN,
                               int* __restrict__ poolidx) {
    int f = blockIdx.x * 256 + threadIdx.x;
    if (f >= FLATN) return;
    int n = min(max(nid[f], 0), N_TOTAL - 1);
    int pos = atomicAdd(&cursorN[n], 1);
    poolidx[pos] = f;
}

// ---------------------------------------------------------------- RWSE ----

__global__ void k_adj(const int* __restrict__ ei, float* __restrict__ T) {
    int e = blockIdx.x * 256 + threadIdx.x;
    if (e >= E_GLOB) return;
    int s = ei[e], d = ei[E_GLOB + e];
    int g = s >> 7;
    atomicAdd(&T[(g * 128 + (s & 127)) * 128 + (d & 127)], 1.0f);
}

__global__ void k_rownorm(float* __restrict__ T) {
    int row = blockIdx.x * 4 + (threadIdx.x >> 6);
    int lane = threadIdx.x & 63;
    float* r = T + (size_t)row * 128;
    float v0 = r[lane], v1 = r[lane + 64];
    float s = v0 + v1;
    #pragma unroll
    for (int off = 32; off > 0; off >>= 1) s += __shfl_down(s, off);
    s = __shfl(s, 0);
    float inv = 1.0f / fmaxf(s, 1.0f);
    r[lane] = v0 * inv;
    r[lane + 64] = v1 * inv;
}

#define RWG 4
#define RWM 32

__global__ __launch_bounds__(256) void k_rwse_mfma(const float* __restrict__ T,
                                                   float* __restrict__ rwse) {
    __shared__ unsigned short P[2][RWM][LDW];
    int g = blockIdx.x / RWG, rb = blockIdx.x % RWG;
    int row0 = rb * RWM;
    int tid = threadIdx.x;
    int w = tid >> 6, l = tid & 63;
    const float* Tg = T + (size_t)g * 16384;

    {
        int r = tid >> 3;
        int c0 = (tid & 7) * 16;
        const float4* src = (const float4*)(Tg + (size_t)(row0 + r) * 128 + c0);
        #pragma unroll
        for (int i = 0; i < 4; ++i) {
            float4 v = src[i];
            ushort4 u;
            u.x = f2bu(v.x); u.y = f2bu(v.y); u.z = f2bu(v.z); u.w = f2bu(v.w);
            *(ushort4*)&P[0][r][c0 + i * 4] = u;
        }
    }
    if (tid < RWM) {
        int gr = row0 + tid;
        rwse[(size_t)(g * 128 + gr) * STEPS] = Tg[(size_t)gr * 128 + gr];
    }

    s16x8 bw[2][4];
    #pragma unroll
    for (int nt = 0; nt < 2; ++nt) {
        int col = w * 32 + nt * 16 + (l & 15);
        #pragma unroll
        for (int kt = 0; kt < 4; ++kt) {
            int k0 = kt * 32 + (l >> 4) * 8;
            #pragma unroll
            for (int j = 0; j < 8; ++j)
                bw[nt][kt][j] = (short)f2bu(Tg[(size_t)(k0 + j) * 128 + col]);
        }
    }
    __syncthreads();

    int cur = 0;
    for (int s = 1; s < STEPS; ++s) {
        f32x4 acc[2][2];
        #pragma unroll
        for (int mt_i = 0; mt_i < 2; ++mt_i)
            #pragma unroll
            for (int nt = 0; nt < 2; ++nt)
                acc[mt_i][nt] = f32x4{0.f, 0.f, 0.f, 0.f};
        #pragma unroll
        for (int kt = 0; kt < 4; ++kt) {
            #pragma unroll
            for (int mt_i = 0; mt_i < 2; ++mt_i) {
                s16x8 a = *(const s16x8*)&P[cur][mt_i * 16 + (l & 15)][kt * 32 + (l >> 4) * 8];
                acc[mt_i][0] = __builtin_amdgcn_mfma_f32_16x16x32_bf16(a, bw[0][kt], acc[mt_i][0], 0, 0, 0);
                acc[mt_i][1] = __builtin_amdgcn_mfma_f32_16x16x32_bf16(a, bw[1][kt], acc[mt_i][1], 0, 0, 0);
            }
        }
        #pragma unroll
        for (int mt_i = 0; mt_i < 2; ++mt_i) {
            #pragma unroll
            for (int nt = 0; nt < 2; ++nt) {
                int col = w * 32 + nt * 16 + (l & 15);
                #pragma unroll
                for (int r = 0; r < 4; ++r) {
                    int lrow = mt_i * 16 + (l >> 4) * 4 + r;
                    P[cur ^ 1][lrow][col] = f2bu(acc[mt_i][nt][r]);
                    if (row0 + lrow == col)
                        rwse[(size_t)(g * 128 + col) * STEPS + s] = acc[mt_i][nt][r];
                }
            }
        }
        __syncthreads();
        cur ^= 1;
    }
}

__global__ void k_rwse_head(const float* __restrict__ rwse, const float* __restrict__ rwse_W,
                            const float* __restrict__ rwse_b, const float* __restrict__ atom_emb,
                            const int* __restrict__ x_ids, float* __restrict__ base) {
    int idx = blockIdx.x * 256 + threadIdx.x;
    int n = idx >> 7, c = idx & 127;
    const float* r = rwse + (size_t)n * STEPS;
    float acc = rwse_b[c];
    #pragma unroll
    for (int s = 0; s < STEPS; ++s) acc += r[s] * rwse_W[s * H + c];
    acc = fmaxf(acc, 0.f);
    base[idx] = acc + atom_emb[x_ids[n] * H + c];
}

__global__ void k_hinit(const float* __restrict__ base, const int* __restrict__ node_ids,
                        bf16* __restrict__ h) {
    int idx = blockIdx.x * 256 + threadIdx.x;
    int f = idx >> 7, c = idx & 127;
    int nidv = node_ids[f];
    int n = min(max(nidv, 0), N_TOTAL - 1);
    float v = base[n * H + c];
    if (nidv < 0) v = 0.f;
    h[idx] = f2b(v);
}

// ---------------------------------------------------------------- GNN -----

// gpool[n] = sum of h rows mapping to n; also zeroes gagg (same index space)
// ahead of k_gagg's atomics (stream-ordered).
__global__ void k_pool_csr(const bf16* __restrict__ h, const int* __restrict__ rpN,
                           const int* __restrict__ degN, const int* __restrict__ poolidx,
                           float* __restrict__ gpool, float* __restrict__ gagg) {
    int idx = blockIdx.x * 256 + threadIdx.x;
    int n = idx >> 7, c = idx & 127;
    gagg[idx] = 0.f;
    float acc = 0.f;
    int beg = rpN[n], end = beg + degN[n];
    for (int j = beg; j < end; ++j) {
        int f = poolidx[j];
        acc += b2f(h[(size_t)f * H + c]);
    }
    gpool[idx] = acc;
}

__global__ void k_gagg(const float* __restrict__ gpool, const float* __restrict__ bond_emb,
                       const int* __restrict__ ei, const int* __restrict__ ea_ids,
                       float* __restrict__ gagg) {
    int idx = blockIdx.x * 256 + threadIdx.x;
    int e = idx >> 7, c = idx & 127;
    int s = ei[e], d = ei[E_GLOB + e];
    float v = fmaxf(gpool[s * H + c] + bond_emb[(ea_ids[e] - 1) * H + c], 0.f);
    atomicAdd(&gagg[d * H + c], v);
}

// z[f] = h[f] + gagg[nid[f]] + sum_e relu(h[src_e] + ea_e), written bf16.
__global__ void k_aggz(const bf16* __restrict__ h, const float* __restrict__ gagg,
                       const float* __restrict__ bond_emb, const int* __restrict__ node_ids,
                       const int* __restrict__ rp, const int* __restrict__ deg,
                       const int* __restrict__ payload, bf16* __restrict__ z) {
    int idx = blockIdx.x * 256 + threadIdx.x;
    int f = idx >> 4, c8 = (idx & 15) << 3;
    int n = min(max(node_ids[f], 0), N_TOTAL - 1);
    float acc[8];
    s16x8 hv = *(const s16x8*)(h + (size_t)f * H + c8);
    const float* gg = gagg + (size_t)n * H + c8;
    #pragma unroll
    for (int j = 0; j < 8; ++j) acc[j] = rb2f(hv[j]) + gg[j];
    int beg = rp[f], end = beg + deg[f];
    for (int e = beg; e < end; ++e) {
        int p = payload[e];
        int src = p >> 3, ea = (p & 7) - 1;
        s16x8 hs = *(const s16x8*)(h + (size_t)src * H + c8);
        const float* be = bond_emb + ea * H + c8;
        #pragma unroll
        for (int j = 0; j < 8; ++j) acc[j] += fmaxf(rb2f(hs[j]) + be[j], 0.f);
    }
    s16x8 o;
    #pragma unroll
    for (int j = 0; j < 8; ++j) o[j] = (short)f2bu(acc[j]);
    *(s16x8*)(z + (size_t)f * H + c8) = o;
}

// Fused GINE MLP: h = (h + W2@relu(W1@z + b1) + b2) * valid, bf16 MFMA.
// Round-9 proven double-buffer structure; h residual loads issued at kernel
// entry (independent of LDS work) so their latency hides under the GEMMs
// instead of sitting in the epilogue tail.
__global__ __launch_bounds__(256) void k_mlp_fused(
    const float* __restrict__ W1, const float* __restrict__ b1,
    const float* __restrict__ W2, const float* __restrict__ b2,
    const bf16* __restrict__ z, const int* __restrict__ node_ids,
    bf16* __restrict__ h) {
    __shared__ unsigned short zt[128][LDW];
    __shared__ unsigned short mt[128][LDW];
    __shared__ float validf[128];

    int tid = threadIdx.x;
    int w = tid >> 6;
    int l = tid & 63;
    int brow0 = blockIdx.x * 128;
    int er = tid >> 1, ec0 = (tid & 1) * 64;   // epilogue/staging row & col base

    // --- issue h residual loads FIRST (independent; latency hides in GEMMs) ---
    s16x8 hres[8];
    {
        const s16x8* hr = (const s16x8*)(h + (size_t)(brow0 + er) * H + ec0);
        #pragma unroll
        for (int i = 0; i < 8; ++i) hres[i] = hr[i];
    }

    // --- stage z tile (bf16 copy) + valid flags ---
    {
        const s16x8* zr = (const s16x8*)(z + (size_t)(brow0 + er) * H + ec0);
        #pragma unroll
        for (int i = 0; i < 8; ++i)
            *(s16x8*)&zt[er][ec0 + i * 8] = zr[i];
        if (tid < 128) validf[tid] = (node_ids[brow0 + tid] >= 0) ? 1.f : 0.f;
    }

    // --- W1/W2 fragments upfront (overlap with staging latency) ---
    s16x8 bw1[2][4], bw2[2][4];
    float b1c[2], b2c[2];
    #pragma unroll
    for (int nt = 0; nt < 2; ++nt) {
        int col = w * 32 + nt * 16 + (l & 15);
        b1c[nt] = b1[col];
        b2c[nt] = b2[col];
        #pragma unroll
        for (int kt = 0; kt < 4; ++kt) {
            int k0 = kt * 32 + (l >> 4) * 8;
            #pragma unroll
            for (int j = 0; j < 8; ++j) {
                bw1[nt][kt][j] = (short)f2bu(W1[(size_t)(k0 + j) * H + col]);
                bw2[nt][kt][j] = (short)f2bu(W2[(size_t)(k0 + j) * H + col]);
            }
        }
    }
    __syncthreads();

    // --- GEMM1: mid = relu(z @ W1 + b1) ---
    f32x4 acc[8][2];
    #pragma unroll
    for (int mt_i = 0; mt_i < 8; ++mt_i)
        #pragma unroll
        for (int nt = 0; nt < 2; ++nt)
            acc[mt_i][nt] = f32x4{0.f, 0.f, 0.f, 0.f};
    #pragma unroll
    for (int kt = 0; kt < 4; ++kt) {
        #pragma unroll
        for (int mt_i = 0; mt_i < 8; ++mt_i) {
            s16x8 a = *(const s16x8*)&zt[mt_i * 16 + (l & 15)][kt * 32 + (l >> 4) * 8];
            acc[mt_i][0] = __builtin_amdgcn_mfma_f32_16x16x32_bf16(a, bw1[0][kt], acc[mt_i][0], 0, 0, 0);
            acc[mt_i][1] = __builtin_amdgcn_mfma_f32_16x16x32_bf16(a, bw1[1][kt], acc[mt_i][1], 0, 0, 0);
        }
    }
    #pragma unroll
    for (int mt_i = 0; mt_i < 8; ++mt_i) {
        #pragma unroll
        for (int nt = 0; nt < 2; ++nt) {
            int col = w * 32 + nt * 16 + (l & 15);
            #pragma unroll
            for (int r = 0; r < 4; ++r) {
                int row = mt_i * 16 + (l >> 4) * 4 + r;
                mt[row][col] = f2bu(fmaxf(acc[mt_i][nt][r] + b1c[nt], 0.f));
            }
        }
    }
    __syncthreads();

    // --- GEMM2: out = mid @ W2 ---
    #pragma unroll
    for (int mt_i = 0; mt_i < 8; ++mt_i)
        #pragma unroll
        for (int nt = 0; nt < 2; ++nt)
            acc[mt_i][nt] = f32x4{0.f, 0.f, 0.f, 0.f};
    #pragma unroll
    for (int kt = 0; kt < 4; ++kt) {
        #pragma unroll
        for (int mt_i = 0; mt_i < 8; ++mt_i) {
            s16x8 a = *(const s16x8*)&mt[mt_i * 16 + (l & 15)][kt * 32 + (l >> 4) * 8];
            acc[mt_i][0] = __builtin_amdgcn_mfma_f32_16x16x32_bf16(a, bw2[0][kt], acc[mt_i][0], 0, 0, 0);
            acc[mt_i][1] = __builtin_amdgcn_mfma_f32_16x16x32_bf16(a, bw2[1][kt], acc[mt_i][1], 0, 0, 0);
        }
    }
    __syncthreads();   // all mid reads done; mt reusable for the output bounce

    // --- epilogue: bounce out+b2 through mt, then coalesced residual RMW ---
    #pragma unroll
    for (int mt_i = 0; mt_i < 8; ++mt_i) {
        #pragma unroll
        for (int nt = 0; nt < 2; ++nt) {
            int col = w * 32 + nt * 16 + (l & 15);
            #pragma unroll
            for (int r = 0; r < 4; ++r) {
                int row = mt_i * 16 + (l >> 4) * 4 + r;
                mt[row][col] = f2bu(acc[mt_i][nt][r] + b2c[nt]);
            }
        }
    }
    __syncthreads();
    {
        float vf = validf[er];
        s16x8* hr = (s16x8*)(h + (size_t)(brow0 + er) * H + ec0);
        #pragma unroll
        for (int i = 0; i < 8; ++i) {
            s16x8 ov = *(const s16x8*)&mt[er][ec0 + i * 8];
            s16x8 o;
            #pragma unroll
            for (int j = 0; j < 8; ++j)
                o[j] = (short)f2bu((rb2f(hres[i][j]) + rb2f(ov[j])) * vf);
            hr[i] = o;
        }
    }
}

// ------------------------------------------------------------- Readout ---

__global__ void k_tok(const bf16* __restrict__ h, float* __restrict__ htok) {
    int idx = blockIdx.x * 256 + threadIdx.x;
    int s = idx >> 7, c = idx & 127;
    htok[idx] = b2f(h[(size_t)s * K_SUB * H + c]);
}

// K1: LN1 + QKV(MFMA) + attention + Wo(MFMA) + residual.
#define ROQ_STR 408

__global__ __launch_bounds__(256) void k_ro_attn(
    float* __restrict__ htok,
    const float* __restrict__ g1, const float* __restrict__ b1,
    const float* __restrict__ Wqkv, const float* __restrict__ bqkv,
    const float* __restrict__ Wo, const float* __restrict__ bo,
    const float* __restrict__ log_probs, const float* __restrict__ alpha_p) {
    __shared__ unsigned short xn[64][LDW];
    __shared__ unsigned short qkv[64][ROQ_STR];
    __shared__ float lpv[64];
    int tid = threadIdx.x;
    int w = tid >> 6, l = tid & 63;
    int g0 = blockIdx.x * 64;
    float alpha = alpha_p[0];

    {
        int t = tid >> 2, q = tid & 3;
        const float4* xr = (const float4*)(htok + (size_t)(g0 + t) * H + q * 32);
        float x[32]; float s = 0.f, ss = 0.f;
        #pragma unroll
        for (int i = 0; i < 8; ++i) {
            float4 v = xr[i];
            x[i * 4 + 0] = v.x; x[i * 4 + 1] = v.y; x[i * 4 + 2] = v.z; x[i * 4 + 3] = v.w;
            s += v.x + v.y + v.z + v.w;
            ss += v.x * v.x + v.y * v.y + v.z * v.z + v.w * v.w;
        }
        s += __shfl_xor(s, 1); ss += __shfl_xor(ss, 1);
        s += __shfl_xor(s, 2); ss += __shfl_xor(ss, 2);
        float mu = s * (1.f / 128.f);
        float var = ss * (1.f / 128.f) - mu * mu;
        float inv = rsqrtf(var + 1e-5f);
        #pragma unroll
        for (int i = 0; i < 32; ++i) {
            int c = q * 32 + i;
            xn[t][c] = f2bu((x[i] - mu) * inv * g1[c] + b1[c]);
        }
        if (tid < 64) {
            float lp = log_probs[g0 + tid];
            lpv[tid] = isfinite(lp) ? lp : 0.f;
        }
    }
    __syncthreads();

    s16x8 a[4][4];
    #pragma unroll
    for (int mt_i = 0; mt_i < 4; ++mt_i)
        #pragma unroll
        for (int kt = 0; kt < 4; ++kt)
            a[mt_i][kt] = *(const s16x8*)&xn[mt_i * 16 + (l & 15)][kt * 32 + (l >> 4) * 8];

    #pragma unroll
    for (int nt = 0; nt < 6; ++nt) {
        int col = w * 96 + nt * 16 + (l & 15);
        s16x8 bw[4];
        #pragma unroll
        for (int kt = 0; kt < 4; ++kt) {
            int k0 = kt * 32 + (l >> 4) * 8;
            #pragma unroll
            for (int j = 0; j < 8; ++j)
                bw[kt][j] = (short)f2bu(Wqkv[(size_t)(k0 + j) * 384 + col]);
        }
        f32x4 acc[4];
        #pragma unroll
        for (int mt_i = 0; mt_i < 4; ++mt_i) acc[mt_i] = f32x4{0.f, 0.f, 0.f, 0.f};
        #pragma unroll
        for (int kt = 0; kt < 4; ++kt)
            #pragma unroll
            for (int mt_i = 0; mt_i < 4; ++mt_i)
                acc[mt_i] = __builtin_amdgcn_mfma_f32_16x16x32_bf16(a[mt_i][kt], bw[kt], acc[mt_i], 0, 0, 0);
        float bb = bqkv[col];
        #pragma unroll
        for (int mt_i = 0; mt_i < 4; ++mt_i)
            #pragma unroll
            for (int r = 0; r < 4; ++r)
                qkv[mt_i * 16 + (l >> 4) * 4 + r][col] = f2bu(acc[mt_i][r] + bb);
    }
    __syncthreads();

    {
        int node = tid >> 4, hh = (tid >> 2) & 3, ii = tid & 3;
        int t0 = node * 4;
        float qv[32];
        #pragma unroll
        for (int j4 = 0; j4 < 4; ++j4) {
            s16x8 v = *(const s16x8*)&qkv[t0 + ii][hh * 32 + j4 * 8];
            #pragma unroll
            for (int j = 0; j < 8; ++j) qv[j4 * 8 + j] = rb2f(v[j]);
        }
        float sc[4];
        #pragma unroll
        for (int jj = 0; jj < 4; ++jj) {
            float d = 0.f;
            #pragma unroll
            for (int j4 = 0; j4 < 4; ++j4) {
                s16x8 kv = *(const s16x8*)&qkv[t0 + jj][128 + hh * 32 + j4 * 8];
                #pragma unroll
                for (int j = 0; j < 8; ++j) d += qv[j4 * 8 + j] * rb2f(kv[j]);
            }
            sc[jj] = d * 0.17677669529663689f + alpha * lpv[t0 + jj];
        }
        float mx = fmaxf(fmaxf(sc[0], sc[1]), fmaxf(sc[2], sc[3]));
        float p[4]; float se = 0.f;
        #pragma unroll
        for (int jj = 0; jj < 4; ++jj) { p[jj] = expf(sc[jj] - mx); se += p[jj]; }
        float inv = 1.f / se;
        #pragma unroll
        for (int jj = 0; jj < 4; ++jj) p[jj] *= inv;
        float ov[32];
        #pragma unroll
        for (int i = 0; i < 32; ++i) ov[i] = 0.f;
        #pragma unroll
        for (int jj = 0; jj < 4; ++jj) {
            #pragma unroll
            for (int j4 = 0; j4 < 4; ++j4) {
                s16x8 vv = *(const s16x8*)&qkv[t0 + jj][256 + hh * 32 + j4 * 8];
                #pragma unroll
                for (int j = 0; j < 8; ++j) ov[j4 * 8 + j] += p[jj] * rb2f(vv[j]);
            }
        }
        __syncthreads();
        #pragma unroll
        for (int j4 = 0; j4 < 4; ++j4) {
            s16x8 o8;
            #pragma unroll
            for (int j = 0; j < 8; ++j) o8[j] = (short)f2bu(ov[j4 * 8 + j]);
            *(s16x8*)&xn[t0 + ii][hh * 32 + j4 * 8] = o8;
        }
    }
    __syncthreads();

    s16x8 ao[4][4];
    #pragma unroll
    for (int mt_i = 0; mt_i < 4; ++mt_i)
        #pragma unroll
        for (int kt = 0; kt < 4; ++kt)
            ao[mt_i][kt] = *(const s16x8*)&xn[mt_i * 16 + (l & 15)][kt * 32 + (l >> 4) * 8];
    #pragma unroll
    for (int nt = 0; nt < 2; ++nt) {
        int col = w * 32 + nt * 16 + (l & 15);
        s16x8 bw[4];
        #pragma unroll
        for (int kt = 0; kt < 4; ++kt) {
            int k0 = kt * 32 + (l >> 4) * 8;
            #pragma unroll
            for (int j = 0; j < 8; ++j)
                bw[kt][j] = (short)f2bu(Wo[(size_t)(k0 + j) * H + col]);
        }
        f32x4 acc[4];
        #pragma unroll
        for (int mt_i = 0; mt_i < 4; ++mt_i) acc[mt_i] = f32x4{0.f, 0.f, 0.f, 0.f};
        #pragma unroll
        for (int kt = 0; kt < 4; ++kt)
            #pragma unroll
            for (int mt_i = 0; mt_i < 4; ++mt_i)
                acc[mt_i] = __builtin_amdgcn_mfma_f32_16x16x32_bf16(ao[mt_i][kt], bw[kt], acc[mt_i], 0, 0, 0);
        float bb = bo[col];
        #pragma unroll
        for (int mt_i = 0; mt_i < 4; ++mt_i)
            #pragma unroll
            for (int r = 0; r < 4; ++r) {
                int row = mt_i * 16 + (l >> 4) * 4 + r;
                size_t gg = (size_t)(g0 + row) * H + col;
                htok[gg] += acc[mt_i][r] + bb;
            }
    }
}

// K2: LN2 + FFN1(gelu) + FFN2 (K-blocked) + residual.
__global__ __launch_bounds__(256) void k_ro_ffn(
    float* __restrict__ htok,
    const float* __restrict__ g2, const float* __restrict__ b2,
    const float* __restrict__ Wf1, const float* __restrict__ bf1,
    const float* __restrict__ Wf2, const float* __restrict__ bf2) {
    __shared__ unsigned short xb[64][LDW];
    int tid = threadIdx.x;
    int w = tid >> 6, l = tid & 63;
    int g0 = blockIdx.x * 64;

    {
        int t = tid >> 2, q = tid & 3;
        const float4* xr = (const float4*)(htok + (size_t)(g0 + t) * H + q * 32);
        float x[32]; float s = 0.f, ss = 0.f;
        #pragma unroll
        for (int i = 0; i < 8; ++i) {
            float4 v = xr[i];
            x[i * 4 + 0] = v.x; x[i * 4 + 1] = v.y; x[i * 4 + 2] = v.z; x[i * 4 + 3] = v.w;
            s += v.x + v.y + v.z + v.w;
            ss += v.x * v.x + v.y * v.y + v.z * v.z + v.w * v.w;
        }
        s += __shfl_xor(s, 1); ss += __shfl_xor(ss, 1);
        s += __shfl_xor(s, 2); ss += __shfl_xor(ss, 2);
        float mu = s * (1.f / 128.f);
        float var = ss * (1.f / 128.f) - mu * mu;
        float inv = rsqrtf(var + 1e-5f);
        #pragma unroll
        for (int i = 0; i < 32; ++i) {
            int c = q * 32 + i;
            xb[t][c] = f2bu((x[i] - mu) * inv * g2[c] + b2[c]);
        }
    }
    __syncthreads();

    s16x8 a2[4][4];
    #pragma unroll
    for (int mt_i = 0; mt_i < 4; ++mt_i)
        #pragma unroll
        for (int kt = 0; kt < 4; ++kt)
            a2[mt_i][kt] = *(const s16x8*)&xb[mt_i * 16 + (l & 15)][kt * 32 + (l >> 4) * 8];
    __syncthreads();

    f32x4 acc2[4][2];
    #pragma unroll
    for (int mt_i = 0; mt_i < 4; ++mt_i)
        #pragma unroll
        for (int nt = 0; nt < 2; ++nt)
            acc2[mt_i][nt] = f32x4{0.f, 0.f, 0.f, 0.f};

    #pragma unroll
    for (int cc = 0; cc < 4; ++cc) {
        #pragma unroll
        for (int nt = 0; nt < 2; ++nt) {
            int colf = cc * 128 + w * 32 + nt * 16 + (l & 15);
            s16x8 bw[4];
            #pragma unroll
            for (int kt = 0; kt < 4; ++kt) {
                int k0 = kt * 32 + (l >> 4) * 8;
                #pragma unroll
                for (int j = 0; j < 8; ++j)
                    bw[kt][j] = (short)f2bu(Wf1[(size_t)(k0 + j) * FFN + colf]);
            }
            f32x4 accm[4];
            #pragma unroll
            for (int mt_i = 0; mt_i < 4; ++mt_i) accm[mt_i] = f32x4{0.f, 0.f, 0.f, 0.f};
            #pragma unroll
            for (int kt = 0; kt < 4; ++kt)
                #pragma unroll
                for (int mt_i = 0; mt_i < 4; ++mt_i)
                    accm[mt_i] = __builtin_amdgcn_mfma_f32_16x16x32_bf16(a2[mt_i][kt], bw[kt], accm[mt_i], 0, 0, 0);
            float bb = bf1[colf];
            int colw = w * 32 + nt * 16 + (l & 15);
            #pragma unroll
            for (int mt_i = 0; mt_i < 4; ++mt_i)
                #pragma unroll
                for (int r = 0; r < 4; ++r) {
                    float v = accm[mt_i][r] + bb;
                    v = v * 0.5f * (1.f + erff(v * 0.70710678118654752f));
                    xb[mt_i * 16 + (l >> 4) * 4 + r][colw] = f2bu(v);
                }
        }
        __syncthreads();
        s16x8 am[4][4];
        #pragma unroll
        for (int mt_i = 0; mt_i < 4; ++mt_i)
            #pragma unroll
            for (int kt = 0; kt < 4; ++kt)
                am[mt_i][kt] = *(const s16x8*)&xb[mt_i * 16 + (l & 15)][kt * 32 + (l >> 4) * 8];
        #pragma unroll
        for (int nt = 0; nt < 2; ++nt) {
            int colo = w * 32 + nt * 16 + (l & 15);
            s16x8 bw[4];
            #pragma unroll
            for (int kt = 0; kt < 4; ++kt) {
                int k0 = cc * 128 + kt * 32 + (l >> 4) * 8;
                #pragma unroll
                for (int j = 0; j < 8; ++j)
                    bw[kt][j] = (short)f2bu(Wf2[(size_t)(k0 + j) * H + colo]);
            }
            #pragma unroll
            for (int kt = 0; kt < 4; ++kt)
                #pragma unroll
                for (int mt_i = 0; mt_i < 4; ++mt_i)
                    acc2[mt_i][nt] = __builtin_amdgcn_mfma_f32_16x16x32_bf16(am[mt_i][kt], bw[kt], acc2[mt_i][nt], 0, 0, 0);
        }
        __syncthreads();
    }

    #pragma unroll
    for (int nt = 0; nt < 2; ++nt) {
        int col = w * 32 + nt * 16 + (l & 15);
        float bb = bf2[col];
        #pragma unroll
        for (int mt_i = 0; mt_i < 4; ++mt_i)
            #pragma unroll
            for (int r = 0; r < 4; ++r) {
                int row = mt_i * 16 + (l >> 4) * 4 + r;
                size_t gg = (size_t)(g0 + row) * H + col;
                htok[gg] += acc2[mt_i][nt][r] + bb;
            }
    }
}

__global__ __launch_bounds__(128) void k_nodeemb(const float* __restrict__ htok,
                                                 const float* __restrict__ og,
                                                 const float* __restrict__ ob,
                                                 float* __restrict__ nemb) {
    int n = blockIdx.x, c = threadIdx.x;
    const float* hr = htok + (size_t)n * 4 * H;
    float v = 0.25f * (hr[c] + hr[H + c] + hr[2 * H + c] + hr[3 * H + c]);
    float s = v, ss = v * v;
    #pragma unroll
    for (int m = 1; m < 64; m <<= 1) { s += __shfl_xor(s, m); ss += __shfl_xor(ss, m); }
    __shared__ float red[4];
    if ((threadIdx.x & 63) == 0) {
        red[(threadIdx.x >> 6) * 2] = s;
        red[(threadIdx.x >> 6) * 2 + 1] = ss;
    }
    __syncthreads();
    s = red[0] + red[2];
    ss = red[1] + red[3];
    float mu = s * (1.f / 128.f);
    float var = ss * (1.f / 128.f) - mu * mu;
    float inv = rsqrtf(var + 1e-5f);
    nemb[(size_t)n * H + c] = (v - mu) * inv * og[c] + ob[c];
}

__global__ __launch_bounds__(128) void k_out(const float* __restrict__ nemb,
                                             float* __restrict__ out) {
    int g = blockIdx.x, c = threadIdx.x;
    float acc = 0.f;
    for (int i = 0; i < 128; ++i) acc += nemb[(size_t)(g * 128 + i) * H + c];
    out[g * H + c] = acc;
}

// ------------------------------------------------------------- launch ----

extern "C" void kernel_launch(void* const* d_in, const int* in_sizes, int n_in,
                              void* d_out, int out_size, void* d_ws, size_t ws_size,
                              hipStream_t stream) {
    (void)in_sizes; (void)n_in; (void)out_size;
    const int* edge_index    = (const int*)d_in[0];
    const int* intra_ei      = (const int*)d_in[1];
    const int* edge_attr_ids = (const int*)d_in[2];
    const int* intra_ea_ids  = (const int*)d_in[3];
    const int* node_ids      = (const int*)d_in[4];
    const int* x_ids         = (const int*)d_in[5];
    const float* log_probs   = (const float*)d_in[7];
    const float* atom_emb    = (const float*)d_in[8];
    const float* bond_emb    = (const float*)d_in[9];
    const float* rwse_W      = (const float*)d_in[10];
    const float* rwse_b      = (const float*)d_in[11];
    const float* gnn_W1      = (const float*)d_in[12];
    const float* gnn_b1      = (const float*)d_in[13];
    const float* gnn_W2      = (const float*)d_in[14];
    const float* gnn_b2      = (const float*)d_in[15];
    const float* ro_ln1_g    = (const float*)d_in[16];
    const float* ro_ln1_b    = (const float*)d_in[17];
    const float* ro_Wqkv     = (const float*)d_in[18];
    const float* ro_bqkv     = (const float*)d_in[19];
    const float* ro_Wo       = (const float*)d_in[20];
    const float* ro_bo       = (const float*)d_in[21];
    const float* ro_ln2_g    = (const float*)d_in[22];
    const float* ro_ln2_b    = (const float*)d_in[23];
    const float* ro_Wf1      = (const float*)d_in[24];
    const float* ro_bf1      = (const float*)d_in[25];
    const float* ro_Wf2      = (const float*)d_in[26];
    const float* ro_bf2      = (const float*)d_in[27];
    const float* out_ln_g    = (const float*)d_in[28];
    const float* out_ln_b    = (const float*)d_in[29];
    const float* ht_alpha    = (const float*)d_in[30];

    char* ws = (char*)d_ws;
    size_t off = 0;
    auto alloc = [&](size_t nbytes) {
        char* p = ws + off;
        off += (nbytes + 255) & ~(size_t)255;
        return p;
    };
    float* T       = (float*)alloc((size_t)B_GRAPHS * 128 * 128 * 4);
    float* rwse    = (float*)alloc((size_t)N_TOTAL * STEPS * 4);
    float* base    = (float*)alloc((size_t)N_TOTAL * H * 4);
    float* gbuf    = (float*)alloc((size_t)2 * N_TOTAL * H * 4);
    float* htok    = (float*)alloc((size_t)S_SUB * H * 4);
    float* nemb    = (float*)alloc((size_t)N_TOTAL * H * 4);
    bf16*  z       = (bf16*)alloc((size_t)FLATN * H * 2);
    bf16*  h       = (bf16*)alloc((size_t)FLATN * H * 2);
    int*   deg     = (int*)alloc((size_t)FLATN * 4);
    int*   rp      = (int*)alloc((size_t)FLATN * 4);
    int*   cursor  = (int*)alloc((size_t)FLATN * 4);
    int*   payload = (int*)alloc((size_t)E_INTRA * 4);
    int*   degN    = (int*)alloc((size_t)N_TOTAL * 4);
    int*   rpN     = (int*)alloc((size_t)N_TOTAL * 4);
    int*   cursorN = (int*)alloc((size_t)N_TOTAL * 4);
    int*   poolidx = (int*)alloc((size_t)FLATN * 4);
    int*   bsum    = (int*)alloc(1024 * 4);
    int*   bsumN   = (int*)alloc(16 * 4);
    float* gpool   = gbuf;
    float* gagg    = gbuf + (size_t)N_TOTAL * H;

    if (off > ws_size) return;

    // ---- CSR build ----
    k_zeroi<<<FLATN / 256, 256, 0, stream>>>(deg, FLATN);
    k_zeroi<<<N_TOTAL / 256, 256, 0, stream>>>(degN, N_TOTAL);
    k_hist_edge<<<E_INTRA / 256, 256, 0, stream>>>(intra_ei, deg);
    k_hist_pool<<<FLATN / 256, 256, 0, stream>>>(node_ids, degN);
    k_scan_blk<<<FLATN / 256, 256, 0, stream>>>(deg, rp, bsum, FLATN);
    k_scan_top<<<1, 256, 0, stream>>>(bsum, FLATN / 256);
    k_scan_add<<<FLATN / 256, 256, 0, stream>>>(rp, bsum, cursor, FLATN);
    k_scan_blk<<<N_TOTAL / 256, 256, 0, stream>>>(degN, rpN, bsumN, N_TOTAL);
    k_scan_top<<<1, 256, 0, stream>>>(bsumN, N_TOTAL / 256);
    k_scan_add<<<N_TOTAL / 256, 256, 0, stream>>>(rpN, bsumN, cursorN, N_TOTAL);
    k_scatter_edge<<<E_INTRA / 256, 256, 0, stream>>>(intra_ei, intra_ea_ids, cursor, payload);
    k_scatter_pool<<<FLATN / 256, 256, 0, stream>>>(node_ids, cursorN, poolidx);

    // ---- RWSE ----
    k_zero4<<<(B_GRAPHS * 128 * 128 / 4 + 255) / 256, 256, 0, stream>>>((float4*)T, B_GRAPHS * 128 * 128 / 4);
    k_adj<<<E_GLOB / 256, 256, 0, stream>>>(edge_index, T);
    k_rownorm<<<(B_GRAPHS * 128) / 4, 256, 0, stream>>>(T);
    k_rwse_mfma<<<B_GRAPHS * RWG, 256, 0, stream>>>(T, rwse);
    k_rwse_head<<<(N_TOTAL * H) / 256, 256, 0, stream>>>(rwse, rwse_W, rwse_b, atom_emb, x_ids, base);
    k_hinit<<<(FLATN * H) / 256, 256, 0, stream>>>(base, node_ids, h);

    // ---- GNN layers ----
    for (int l = 0; l < L_GNN; ++l) {
        k_pool_csr<<<(N_TOTAL * H) / 256, 256, 0, stream>>>(h, rpN, degN, poolidx, gpool, gagg);
        k_gagg<<<(E_GLOB * H) / 256, 256, 0, stream>>>(gpool, bond_emb, edge_index, edge_attr_ids, gagg);
        k_aggz<<<(FLATN * 16) / 256, 256, 0, stream>>>(h, gagg, bond_emb, node_ids, rp, deg, payload, z);
        k_mlp_fused<<<FLATN / 128, 256, 0, stream>>>(
            gnn_W1 + (size_t)l * H * H, gnn_b1 + l * H,
            gnn_W2 + (size_t)l * H * H, gnn_b2 + l * H,
            z, node_ids, h);
    }

    // ---- Readout ----
    k_tok<<<(S_SUB * H) / 256, 256, 0, stream>>>(h, htok);
    for (int l = 0; l < L_RO; ++l) {
        k_ro_attn<<<S_SUB * M_TOK / 64 / 4, 256, 0, stream>>>(htok,
            ro_ln1_g + l * H, ro_ln1_b + l * H,
            ro_Wqkv + (size_t)l * H * 3 * H, ro_bqkv + l * 3 * H,
            ro_Wo + (size_t)l * H * H, ro_bo + l * H,
            log_probs, ht_alpha);
        k_ro_ffn<<<S_SUB * M_TOK / 64 / 4, 256, 0, stream>>>(htok,
            ro_ln2_g + l * H, ro_ln2_b + l * H,
            ro_Wf1 + (size_t)l * H * FFN, ro_bf1 + l * FFN,
            ro_Wf2 + (size_t)l * FFN * H, ro_bf2 + l * H);
    }
    k_nodeemb<<<N_TOTAL, 128, 0, stream>>>(htok, out_ln_g, out_ln_b, nemb);
    k_out<<<B_GRAPHS, 128, 0, stream>>>(nemb, (float*)d_out);
}

// Round 12
// 990.300 us; speedup vs baseline: 1.0724x; 1.0651x over previous
//
#include <hip/hip_runtime.h>
#include <hip/hip_bf16.h>
#include <math.h>

#define B_GRAPHS 32
#define NPG 128
#define N_TOTAL 4096
#define M_TOK 4
#define K_SUB 16
#define S_SUB 16384
#define FLATN 262144
#define H 128
#define NH 4
#define DH 32
#define STEPS 16
#define L_GNN 4
#define L_RO 2
#define EDGE_DIM 5
#define E_GLOB 32768
#define E_INTRA 524288
#define FFN 512
#define LDW 136

typedef __hip_bfloat16 bf16;
typedef __attribute__((ext_vector_type(8))) short s16x8;
typedef __attribute__((ext_vector_type(4))) float f32x4;

__device__ __forceinline__ float b2f(bf16 v) { return __bfloat162float(v); }
__device__ __forceinline__ bf16 f2b(float v) { return __float2bfloat16(v); }
__device__ __forceinline__ unsigned short f2bu(float v) {
    bf16 b = __float2bfloat16(v);
    return *(unsigned short*)&b;
}
__device__ __forceinline__ float rb2f(short u) {
    return __uint_as_float(((unsigned int)(unsigned short)u) << 16);
}

// ------------------------------------------------------------- utility ---

__global__ void k_zero4(float4* __restrict__ p, int n4) {
    int i = blockIdx.x * 256 + threadIdx.x;
    if (i < n4) p[i] = make_float4(0.f, 0.f, 0.f, 0.f);
}

__global__ void k_zeroi(int* __restrict__ p, int n) {
    int i = blockIdx.x * 256 + threadIdx.x;
    if (i < n) p[i] = 0;
}

// ------------------------------------------------------------ CSR build --

__global__ void k_hist_edge(const int* __restrict__ iei, int* __restrict__ deg) {
    int e = blockIdx.x * 256 + threadIdx.x;
    if (e < E_INTRA) atomicAdd(&deg[iei[E_INTRA + e]], 1);
}

__global__ void k_hist_pool(const int* __restrict__ nid, int* __restrict__ degN) {
    int f = blockIdx.x * 256 + threadIdx.x;
    if (f < FLATN) atomicAdd(&degN[min(max(nid[f], 0), N_TOTAL - 1)], 1);
}

__global__ __launch_bounds__(256) void k_scan_blk(const int* __restrict__ in,
                                                  int* __restrict__ out,
                                                  int* __restrict__ bsum, int n) {
    __shared__ int s[256];
    int i = blockIdx.x * 256 + threadIdx.x;
    int v = (i < n) ? in[i] : 0;
    s[threadIdx.x] = v;
    __syncthreads();
    #pragma unroll
    for (int off = 1; off < 256; off <<= 1) {
        int t = (threadIdx.x >= off) ? s[threadIdx.x - off] : 0;
        __syncthreads();
        s[threadIdx.x] += t;
        __syncthreads();
    }
    if (i < n) out[i] = s[threadIdx.x] - v;
    if (threadIdx.x == 255) bsum[blockIdx.x] = s[255];
}

__global__ __launch_bounds__(256) void k_scan_top(int* __restrict__ bsum, int nb) {
    __shared__ int s[256];
    int base = threadIdx.x * 4;
    int v[4]; int loc = 0;
    #pragma unroll
    for (int j = 0; j < 4; ++j) {
        v[j] = (base + j < nb) ? bsum[base + j] : 0;
        loc += v[j];
    }
    s[threadIdx.x] = loc;
    __syncthreads();
    #pragma unroll
    for (int off = 1; off < 256; off <<= 1) {
        int t = (threadIdx.x >= off) ? s[threadIdx.x - off] : 0;
        __syncthreads();
        s[threadIdx.x] += t;
        __syncthreads();
    }
    int run = s[threadIdx.x] - loc;
    #pragma unroll
    for (int j = 0; j < 4; ++j) {
        if (base + j < nb) bsum[base + j] = run;
        run += v[j];
    }
}

__global__ void k_scan_add(int* __restrict__ out, const int* __restrict__ bsum,
                           int* __restrict__ cursor, int n) {
    int i = blockIdx.x * 256 + threadIdx.x;
    if (i < n) {
        int v = out[i] + bsum[i >> 8];
        out[i] = v;
        cursor[i] = v;
    }
}

__global__ void k_scatter_edge(const int* __restrict__ iei, const int* __restrict__ iea,
                               int* __restrict__ cursor, int* __restrict__ payload) {
    int e = blockIdx.x * 256 + threadIdx.x;
    if (e >= E_INTRA) return;
    int d = iei[E_INTRA + e];
    int pos = atomicAdd(&cursor[d], 1);
    payload[pos] = (iei[e] << 3) | iea[e];
}

__global__ void k_scatter_pool(const int* __restrict__ nid, int* __restrict__ cursorN,
                               int* __restrict__ poolidx) {
    int f = blockIdx.x * 256 + threadIdx.x;
    if (f >= FLATN) return;
    int n = min(max(nid[f], 0), N_TOTAL - 1);
    int pos = atomicAdd(&cursorN[n], 1);
    poolidx[pos] = f;
}

// ---------------------------------------------------------------- RWSE ----

__global__ void k_adj(const int* __restrict__ ei, float* __restrict__ T) {
    int e = blockIdx.x * 256 + threadIdx.x;
    if (e >= E_GLOB) return;
    int s = ei[e], d = ei[E_GLOB + e];
    int g = s >> 7;
    atomicAdd(&T[(g * 128 + (s & 127)) * 128 + (d & 127)], 1.0f);
}

__global__ void k_rownorm(float* __restrict__ T) {
    int row = blockIdx.x * 4 + (threadIdx.x >> 6);
    int lane = threadIdx.x & 63;
    float* r = T + (size_t)row * 128;
    float v0 = r[lane], v1 = r[lane + 64];
    float s = v0 + v1;
    #pragma unroll
    for (int off = 32; off > 0; off >>= 1) s += __shfl_down(s, off);
    s = __shfl(s, 0);
    float inv = 1.0f / fmaxf(s, 1.0f);
    r[lane] = v0 * inv;
    r[lane + 64] = v1 * inv;
}

#define RWG 4
#define RWM 32

__global__ __launch_bounds__(256) void k_rwse_mfma(const float* __restrict__ T,
                                                   float* __restrict__ rwse) {
    __shared__ unsigned short P[2][RWM][LDW];
    int g = blockIdx.x / RWG, rb = blockIdx.x % RWG;
    int row0 = rb * RWM;
    int tid = threadIdx.x;
    int w = tid >> 6, l = tid & 63;
    const float* Tg = T + (size_t)g * 16384;

    {
        int r = tid >> 3;
        int c0 = (tid & 7) * 16;
        const float4* src = (const float4*)(Tg + (size_t)(row0 + r) * 128 + c0);
        #pragma unroll
        for (int i = 0; i < 4; ++i) {
            float4 v = src[i];
            ushort4 u;
            u.x = f2bu(v.x); u.y = f2bu(v.y); u.z = f2bu(v.z); u.w = f2bu(v.w);
            *(ushort4*)&P[0][r][c0 + i * 4] = u;
        }
    }
    if (tid < RWM) {
        int gr = row0 + tid;
        rwse[(size_t)(g * 128 + gr) * STEPS] = Tg[(size_t)gr * 128 + gr];
    }

    s16x8 bw[2][4];
    #pragma unroll
    for (int nt = 0; nt < 2; ++nt) {
        int col = w * 32 + nt * 16 + (l & 15);
        #pragma unroll
        for (int kt = 0; kt < 4; ++kt) {
            int k0 = kt * 32 + (l >> 4) * 8;
            #pragma unroll
            for (int j = 0; j < 8; ++j)
                bw[nt][kt][j] = (short)f2bu(Tg[(size_t)(k0 + j) * 128 + col]);
        }
    }
    __syncthreads();

    int cur = 0;
    for (int s = 1; s < STEPS; ++s) {
        f32x4 acc[2][2];
        #pragma unroll
        for (int mt_i = 0; mt_i < 2; ++mt_i)
            #pragma unroll
            for (int nt = 0; nt < 2; ++nt)
                acc[mt_i][nt] = f32x4{0.f, 0.f, 0.f, 0.f};
        #pragma unroll
        for (int kt = 0; kt < 4; ++kt) {
            #pragma unroll
            for (int mt_i = 0; mt_i < 2; ++mt_i) {
                s16x8 a = *(const s16x8*)&P[cur][mt_i * 16 + (l & 15)][kt * 32 + (l >> 4) * 8];
                acc[mt_i][0] = __builtin_amdgcn_mfma_f32_16x16x32_bf16(a, bw[0][kt], acc[mt_i][0], 0, 0, 0);
                acc[mt_i][1] = __builtin_amdgcn_mfma_f32_16x16x32_bf16(a, bw[1][kt], acc[mt_i][1], 0, 0, 0);
            }
        }
        #pragma unroll
        for (int mt_i = 0; mt_i < 2; ++mt_i) {
            #pragma unroll
            for (int nt = 0; nt < 2; ++nt) {
                int col = w * 32 + nt * 16 + (l & 15);
                #pragma unroll
                for (int r = 0; r < 4; ++r) {
                    int lrow = mt_i * 16 + (l >> 4) * 4 + r;
                    P[cur ^ 1][lrow][col] = f2bu(acc[mt_i][nt][r]);
                    if (row0 + lrow == col)
                        rwse[(size_t)(g * 128 + col) * STEPS + s] = acc[mt_i][nt][r];
                }
            }
        }
        __syncthreads();
        cur ^= 1;
    }
}

__global__ void k_rwse_head(const float* __restrict__ rwse, const float* __restrict__ rwse_W,
                            const float* __restrict__ rwse_b, const float* __restrict__ atom_emb,
                            const int* __restrict__ x_ids, float* __restrict__ base) {
    int idx = blockIdx.x * 256 + threadIdx.x;
    int n = idx >> 7, c = idx & 127;
    const float* r = rwse + (size_t)n * STEPS;
    float acc = rwse_b[c];
    #pragma unroll
    for (int s = 0; s < STEPS; ++s) acc += r[s] * rwse_W[s * H + c];
    acc = fmaxf(acc, 0.f);
    base[idx] = acc + atom_emb[x_ids[n] * H + c];
}

__global__ void k_hinit(const float* __restrict__ base, const int* __restrict__ node_ids,
                        bf16* __restrict__ h) {
    int idx = blockIdx.x * 256 + threadIdx.x;
    int f = idx >> 7, c = idx & 127;
    int nidv = node_ids[f];
    int n = min(max(nidv, 0), N_TOTAL - 1);
    float v = base[n * H + c];
    if (nidv < 0) v = 0.f;
    h[idx] = f2b(v);
}

// ---------------------------------------------------------------- GNN -----

// gpool[n] = sum of h rows mapping to n; also zeroes gagg (same index space)
// ahead of k_gagg's atomics (stream-ordered).
__global__ void k_pool_csr(const bf16* __restrict__ h, const int* __restrict__ rpN,
                           const int* __restrict__ degN, const int* __restrict__ poolidx,
                           float* __restrict__ gpool, float* __restrict__ gagg) {
    int idx = blockIdx.x * 256 + threadIdx.x;
    int n = idx >> 7, c = idx & 127;
    gagg[idx] = 0.f;
    float acc = 0.f;
    int beg = rpN[n], end = beg + degN[n];
    for (int j = beg; j < end; ++j) {
        int f = poolidx[j];
        acc += b2f(h[(size_t)f * H + c]);
    }
    gpool[idx] = acc;
}

__global__ void k_gagg(const float* __restrict__ gpool, const float* __restrict__ bond_emb,
                       const int* __restrict__ ei, const int* __restrict__ ea_ids,
                       float* __restrict__ gagg) {
    int idx = blockIdx.x * 256 + threadIdx.x;
    int e = idx >> 7, c = idx & 127;
    int s = ei[e], d = ei[E_GLOB + e];
    float v = fmaxf(gpool[s * H + c] + bond_emb[(ea_ids[e] - 1) * H + c], 0.f);
    atomicAdd(&gagg[d * H + c], v);
}

// z[f] = h[f] + gagg[nid[f]] + sum_e relu(h[src_e] + ea_e), written bf16.
__global__ void k_aggz(const bf16* __restrict__ h, const float* __restrict__ gagg,
                       const float* __restrict__ bond_emb, const int* __restrict__ node_ids,
                       const int* __restrict__ rp, const int* __restrict__ deg,
                       const int* __restrict__ payload, bf16* __restrict__ z) {
    int idx = blockIdx.x * 256 + threadIdx.x;
    int f = idx >> 4, c8 = (idx & 15) << 3;
    int n = min(max(node_ids[f], 0), N_TOTAL - 1);
    float acc[8];
    s16x8 hv = *(const s16x8*)(h + (size_t)f * H + c8);
    const float* gg = gagg + (size_t)n * H + c8;
    #pragma unroll
    for (int j = 0; j < 8; ++j) acc[j] = rb2f(hv[j]) + gg[j];
    int beg = rp[f], end = beg + deg[f];
    for (int e = beg; e < end; ++e) {
        int p = payload[e];
        int src = p >> 3, ea = (p & 7) - 1;
        s16x8 hs = *(const s16x8*)(h + (size_t)src * H + c8);
        const float* be = bond_emb + ea * H + c8;
        #pragma unroll
        for (int j = 0; j < 8; ++j) acc[j] += fmaxf(rb2f(hs[j]) + be[j], 0.f);
    }
    s16x8 o;
    #pragma unroll
    for (int j = 0; j < 8; ++j) o[j] = (short)f2bu(acc[j]);
    *(s16x8*)(z + (size_t)f * H + c8) = o;
}

// Fused GINE MLP: h = (h + W2@relu(W1@z + b1) + b2) * valid, bf16 MFMA.
// Round-9 local optimum: double LDS buffer, W1+W2 upfront, coalesced
// LDS-bounced residual epilogue. Perturbations tested and rejected:
// fused gather (R7), single buffer (R8/R10), h-prefetch (R11).
__global__ __launch_bounds__(256) void k_mlp_fused(
    const float* __restrict__ W1, const float* __restrict__ b1,
    const float* __restrict__ W2, const float* __restrict__ b2,
    const bf16* __restrict__ z, const int* __restrict__ node_ids,
    bf16* __restrict__ h) {
    __shared__ unsigned short zt[128][LDW];
    __shared__ unsigned short mt[128][LDW];
    __shared__ float validf[128];

    int tid = threadIdx.x;
    int w = tid >> 6;
    int l = tid & 63;
    int brow0 = blockIdx.x * 128;

    // --- stage z tile (bf16 copy) + valid flags ---
    {
        int r = tid >> 1, c0 = (tid & 1) * 64;
        const s16x8* zr = (const s16x8*)(z + (size_t)(brow0 + r) * H + c0);
        #pragma unroll
        for (int i = 0; i < 8; ++i)
            *(s16x8*)&zt[r][c0 + i * 8] = zr[i];
        if (tid < 128) validf[tid] = (node_ids[brow0 + tid] >= 0) ? 1.f : 0.f;
    }

    // --- W1/W2 fragments upfront (overlap with staging latency) ---
    s16x8 bw1[2][4], bw2[2][4];
    float b1c[2], b2c[2];
    #pragma unroll
    for (int nt = 0; nt < 2; ++nt) {
        int col = w * 32 + nt * 16 + (l & 15);
        b1c[nt] = b1[col];
        b2c[nt] = b2[col];
        #pragma unroll
        for (int kt = 0; kt < 4; ++kt) {
            int k0 = kt * 32 + (l >> 4) * 8;
            #pragma unroll
            for (int j = 0; j < 8; ++j) {
                bw1[nt][kt][j] = (short)f2bu(W1[(size_t)(k0 + j) * H + col]);
                bw2[nt][kt][j] = (short)f2bu(W2[(size_t)(k0 + j) * H + col]);
            }
        }
    }
    __syncthreads();

    // --- GEMM1: mid = relu(z @ W1 + b1) ---
    f32x4 acc[8][2];
    #pragma unroll
    for (int mt_i = 0; mt_i < 8; ++mt_i)
        #pragma unroll
        for (int nt = 0; nt < 2; ++nt)
            acc[mt_i][nt] = f32x4{0.f, 0.f, 0.f, 0.f};
    #pragma unroll
    for (int kt = 0; kt < 4; ++kt) {
        #pragma unroll
        for (int mt_i = 0; mt_i < 8; ++mt_i) {
            s16x8 a = *(const s16x8*)&zt[mt_i * 16 + (l & 15)][kt * 32 + (l >> 4) * 8];
            acc[mt_i][0] = __builtin_amdgcn_mfma_f32_16x16x32_bf16(a, bw1[0][kt], acc[mt_i][0], 0, 0, 0);
            acc[mt_i][1] = __builtin_amdgcn_mfma_f32_16x16x32_bf16(a, bw1[1][kt], acc[mt_i][1], 0, 0, 0);
        }
    }
    #pragma unroll
    for (int mt_i = 0; mt_i < 8; ++mt_i) {
        #pragma unroll
        for (int nt = 0; nt < 2; ++nt) {
            int col = w * 32 + nt * 16 + (l & 15);
            #pragma unroll
            for (int r = 0; r < 4; ++r) {
                int row = mt_i * 16 + (l >> 4) * 4 + r;
                mt[row][col] = f2bu(fmaxf(acc[mt_i][nt][r] + b1c[nt], 0.f));
            }
        }
    }
    __syncthreads();

    // --- GEMM2: out = mid @ W2 ---
    #pragma unroll
    for (int mt_i = 0; mt_i < 8; ++mt_i)
        #pragma unroll
        for (int nt = 0; nt < 2; ++nt)
            acc[mt_i][nt] = f32x4{0.f, 0.f, 0.f, 0.f};
    #pragma unroll
    for (int kt = 0; kt < 4; ++kt) {
        #pragma unroll
        for (int mt_i = 0; mt_i < 8; ++mt_i) {
            s16x8 a = *(const s16x8*)&mt[mt_i * 16 + (l & 15)][kt * 32 + (l >> 4) * 8];
            acc[mt_i][0] = __builtin_amdgcn_mfma_f32_16x16x32_bf16(a, bw2[0][kt], acc[mt_i][0], 0, 0, 0);
            acc[mt_i][1] = __builtin_amdgcn_mfma_f32_16x16x32_bf16(a, bw2[1][kt], acc[mt_i][1], 0, 0, 0);
        }
    }
    __syncthreads();   // all mid reads done; mt reusable for the output bounce

    // --- epilogue: bounce out+b2 through mt, then coalesced residual RMW ---
    #pragma unroll
    for (int mt_i = 0; mt_i < 8; ++mt_i) {
        #pragma unroll
        for (int nt = 0; nt < 2; ++nt) {
            int col = w * 32 + nt * 16 + (l & 15);
            #pragma unroll
            for (int r = 0; r < 4; ++r) {
                int row = mt_i * 16 + (l >> 4) * 4 + r;
                mt[row][col] = f2bu(acc[mt_i][nt][r] + b2c[nt]);
            }
        }
    }
    __syncthreads();
    {
        int r = tid >> 1, c0 = (tid & 1) * 64;
        float vf = validf[r];
        s16x8* hr = (s16x8*)(h + (size_t)(brow0 + r) * H + c0);
        #pragma unroll
        for (int i = 0; i < 8; ++i) {
            s16x8 hv = hr[i];
            s16x8 ov = *(const s16x8*)&mt[r][c0 + i * 8];
            s16x8 o;
            #pragma unroll
            for (int j = 0; j < 8; ++j)
                o[j] = (short)f2bu((rb2f(hv[j]) + rb2f(ov[j])) * vf);
            hr[i] = o;
        }
    }
}

// ------------------------------------------------------------- Readout ---

__global__ void k_tok(const bf16* __restrict__ h, float* __restrict__ htok) {
    int idx = blockIdx.x * 256 + threadIdx.x;
    int s = idx >> 7, c = idx & 127;
    htok[idx] = b2f(h[(size_t)s * K_SUB * H + c]);
}

// K1: LN1 + QKV(MFMA) + attention + Wo(MFMA) + residual.
#define ROQ_STR 408

__global__ __launch_bounds__(256) void k_ro_attn(
    float* __restrict__ htok,
    const float* __restrict__ g1, const float* __restrict__ b1,
    const float* __restrict__ Wqkv, const float* __restrict__ bqkv,
    const float* __restrict__ Wo, const float* __restrict__ bo,
    const float* __restrict__ log_probs, const float* __restrict__ alpha_p) {
    __shared__ unsigned short xn[64][LDW];
    __shared__ unsigned short qkv[64][ROQ_STR];
    __shared__ float lpv[64];
    int tid = threadIdx.x;
    int w = tid >> 6, l = tid & 63;
    int g0 = blockIdx.x * 64;
    float alpha = alpha_p[0];

    {
        int t = tid >> 2, q = tid & 3;
        const float4* xr = (const float4*)(htok + (size_t)(g0 + t) * H + q * 32);
        float x[32]; float s = 0.f, ss = 0.f;
        #pragma unroll
        for (int i = 0; i < 8; ++i) {
            float4 v = xr[i];
            x[i * 4 + 0] = v.x; x[i * 4 + 1] = v.y; x[i * 4 + 2] = v.z; x[i * 4 + 3] = v.w;
            s += v.x + v.y + v.z + v.w;
            ss += v.x * v.x + v.y * v.y + v.z * v.z + v.w * v.w;
        }
        s += __shfl_xor(s, 1); ss += __shfl_xor(ss, 1);
        s += __shfl_xor(s, 2); ss += __shfl_xor(ss, 2);
        float mu = s * (1.f / 128.f);
        float var = ss * (1.f / 128.f) - mu * mu;
        float inv = rsqrtf(var + 1e-5f);
        #pragma unroll
        for (int i = 0; i < 32; ++i) {
            int c = q * 32 + i;
            xn[t][c] = f2bu((x[i] - mu) * inv * g1[c] + b1[c]);
        }
        if (tid < 64) {
            float lp = log_probs[g0 + tid];
            lpv[tid] = isfinite(lp) ? lp : 0.f;
        }
    }
    __syncthreads();

    s16x8 a[4][4];
    #pragma unroll
    for (int mt_i = 0; mt_i < 4; ++mt_i)
        #pragma unroll
        for (int kt = 0; kt < 4; ++kt)
            a[mt_i][kt] = *(const s16x8*)&xn[mt_i * 16 + (l & 15)][kt * 32 + (l >> 4) * 8];

    #pragma unroll
    for (int nt = 0; nt < 6; ++nt) {
        int col = w * 96 + nt * 16 + (l & 15);
        s16x8 bw[4];
        #pragma unroll
        for (int kt = 0; kt < 4; ++kt) {
            int k0 = kt * 32 + (l >> 4) * 8;
            #pragma unroll
            for (int j = 0; j < 8; ++j)
                bw[kt][j] = (short)f2bu(Wqkv[(size_t)(k0 + j) * 384 + col]);
        }
        f32x4 acc[4];
        #pragma unroll
        for (int mt_i = 0; mt_i < 4; ++mt_i) acc[mt_i] = f32x4{0.f, 0.f, 0.f, 0.f};
        #pragma unroll
        for (int kt = 0; kt < 4; ++kt)
            #pragma unroll
            for (int mt_i = 0; mt_i < 4; ++mt_i)
                acc[mt_i] = __builtin_amdgcn_mfma_f32_16x16x32_bf16(a[mt_i][kt], bw[kt], acc[mt_i], 0, 0, 0);
        float bb = bqkv[col];
        #pragma unroll
        for (int mt_i = 0; mt_i < 4; ++mt_i)
            #pragma unroll
            for (int r = 0; r < 4; ++r)
                qkv[mt_i * 16 + (l >> 4) * 4 + r][col] = f2bu(acc[mt_i][r] + bb);
    }
    __syncthreads();

    {
        int node = tid >> 4, hh = (tid >> 2) & 3, ii = tid & 3;
        int t0 = node * 4;
        float qv[32];
        #pragma unroll
        for (int j4 = 0; j4 < 4; ++j4) {
            s16x8 v = *(const s16x8*)&qkv[t0 + ii][hh * 32 + j4 * 8];
            #pragma unroll
            for (int j = 0; j < 8; ++j) qv[j4 * 8 + j] = rb2f(v[j]);
        }
        float sc[4];
        #pragma unroll
        for (int jj = 0; jj < 4; ++jj) {
            float d = 0.f;
            #pragma unroll
            for (int j4 = 0; j4 < 4; ++j4) {
                s16x8 kv = *(const s16x8*)&qkv[t0 + jj][128 + hh * 32 + j4 * 8];
                #pragma unroll
                for (int j = 0; j < 8; ++j) d += qv[j4 * 8 + j] * rb2f(kv[j]);
            }
            sc[jj] = d * 0.17677669529663689f + alpha * lpv[t0 + jj];
        }
        float mx = fmaxf(fmaxf(sc[0], sc[1]), fmaxf(sc[2], sc[3]));
        float p[4]; float se = 0.f;
        #pragma unroll
        for (int jj = 0; jj < 4; ++jj) { p[jj] = expf(sc[jj] - mx); se += p[jj]; }
        float inv = 1.f / se;
        #pragma unroll
        for (int jj = 0; jj < 4; ++jj) p[jj] *= inv;
        float ov[32];
        #pragma unroll
        for (int i = 0; i < 32; ++i) ov[i] = 0.f;
        #pragma unroll
        for (int jj = 0; jj < 4; ++jj) {
            #pragma unroll
            for (int j4 = 0; j4 < 4; ++j4) {
                s16x8 vv = *(const s16x8*)&qkv[t0 + jj][256 + hh * 32 + j4 * 8];
                #pragma unroll
                for (int j = 0; j < 8; ++j) ov[j4 * 8 + j] += p[jj] * rb2f(vv[j]);
            }
        }
        __syncthreads();
        #pragma unroll
        for (int j4 = 0; j4 < 4; ++j4) {
            s16x8 o8;
            #pragma unroll
            for (int j = 0; j < 8; ++j) o8[j] = (short)f2bu(ov[j4 * 8 + j]);
            *(s16x8*)&xn[t0 + ii][hh * 32 + j4 * 8] = o8;
        }
    }
    __syncthreads();

    s16x8 ao[4][4];
    #pragma unroll
    for (int mt_i = 0; mt_i < 4; ++mt_i)
        #pragma unroll
        for (int kt = 0; kt < 4; ++kt)
            ao[mt_i][kt] = *(const s16x8*)&xn[mt_i * 16 + (l & 15)][kt * 32 + (l >> 4) * 8];
    #pragma unroll
    for (int nt = 0; nt < 2; ++nt) {
        int col = w * 32 + nt * 16 + (l & 15);
        s16x8 bw[4];
        #pragma unroll
        for (int kt = 0; kt < 4; ++kt) {
            int k0 = kt * 32 + (l >> 4) * 8;
            #pragma unroll
            for (int j = 0; j < 8; ++j)
                bw[kt][j] = (short)f2bu(Wo[(size_t)(k0 + j) * H + col]);
        }
        f32x4 acc[4];
        #pragma unroll
        for (int mt_i = 0; mt_i < 4; ++mt_i) acc[mt_i] = f32x4{0.f, 0.f, 0.f, 0.f};
        #pragma unroll
        for (int kt = 0; kt < 4; ++kt)
            #pragma unroll
            for (int mt_i = 0; mt_i < 4; ++mt_i)
                acc[mt_i] = __builtin_amdgcn_mfma_f32_16x16x32_bf16(ao[mt_i][kt], bw[kt], acc[mt_i], 0, 0, 0);
        float bb = bo[col];
        #pragma unroll
        for (int mt_i = 0; mt_i < 4; ++mt_i)
            #pragma unroll
            for (int r = 0; r < 4; ++r) {
                int row = mt_i * 16 + (l >> 4) * 4 + r;
                size_t gg = (size_t)(g0 + row) * H + col;
                htok[gg] += acc[mt_i][r] + bb;
            }
    }
}

// K2: LN2 + FFN1(gelu) + FFN2 (K-blocked) + residual.
__global__ __launch_bounds__(256) void k_ro_ffn(
    float* __restrict__ htok,
    const float* __restrict__ g2, const float* __restrict__ b2,
    const float* __restrict__ Wf1, const float* __restrict__ bf1,
    const float* __restrict__ Wf2, const float* __restrict__ bf2) {
    __shared__ unsigned short xb[64][LDW];
    int tid = threadIdx.x;
    int w = tid >> 6, l = tid & 63;
    int g0 = blockIdx.x * 64;

    {
        int t = tid >> 2, q = tid & 3;
        const float4* xr = (const float4*)(htok + (size_t)(g0 + t) * H + q * 32);
        float x[32]; float s = 0.f, ss = 0.f;
        #pragma unroll
        for (int i = 0; i < 8; ++i) {
            float4 v = xr[i];
            x[i * 4 + 0] = v.x; x[i * 4 + 1] = v.y; x[i * 4 + 2] = v.z; x[i * 4 + 3] = v.w;
            s += v.x + v.y + v.z + v.w;
            ss += v.x * v.x + v.y * v.y + v.z * v.z + v.w * v.w;
        }
        s += __shfl_xor(s, 1); ss += __shfl_xor(ss, 1);
        s += __shfl_xor(s, 2); ss += __shfl_xor(ss, 2);
        float mu = s * (1.f / 128.f);
        float var = ss * (1.f / 128.f) - mu * mu;
        float inv = rsqrtf(var + 1e-5f);
        #pragma unroll
        for (int i = 0; i < 32; ++i) {
            int c = q * 32 + i;
            xb[t][c] = f2bu((x[i] - mu) * inv * g2[c] + b2[c]);
        }
    }
    __syncthreads();

    s16x8 a2[4][4];
    #pragma unroll
    for (int mt_i = 0; mt_i < 4; ++mt_i)
        #pragma unroll
        for (int kt = 0; kt < 4; ++kt)
            a2[mt_i][kt] = *(const s16x8*)&xb[mt_i * 16 + (l & 15)][kt * 32 + (l >> 4) * 8];
    __syncthreads();

    f32x4 acc2[4][2];
    #pragma unroll
    for (int mt_i = 0; mt_i < 4; ++mt_i)
        #pragma unroll
        for (int nt = 0; nt < 2; ++nt)
            acc2[mt_i][nt] = f32x4{0.f, 0.f, 0.f, 0.f};

    #pragma unroll
    for (int cc = 0; cc < 4; ++cc) {
        #pragma unroll
        for (int nt = 0; nt < 2; ++nt) {
            int colf = cc * 128 + w * 32 + nt * 16 + (l & 15);
            s16x8 bw[4];
            #pragma unroll
            for (int kt = 0; kt < 4; ++kt) {
                int k0 = kt * 32 + (l >> 4) * 8;
                #pragma unroll
                for (int j = 0; j < 8; ++j)
                    bw[kt][j] = (short)f2bu(Wf1[(size_t)(k0 + j) * FFN + colf]);
            }
            f32x4 accm[4];
            #pragma unroll
            for (int mt_i = 0; mt_i < 4; ++mt_i) accm[mt_i] = f32x4{0.f, 0.f, 0.f, 0.f};
            #pragma unroll
            for (int kt = 0; kt < 4; ++kt)
                #pragma unroll
                for (int mt_i = 0; mt_i < 4; ++mt_i)
                    accm[mt_i] = __builtin_amdgcn_mfma_f32_16x16x32_bf16(a2[mt_i][kt], bw[kt], accm[mt_i], 0, 0, 0);
            float bb = bf1[colf];
            int colw = w * 32 + nt * 16 + (l & 15);
            #pragma unroll
            for (int mt_i = 0; mt_i < 4; ++mt_i)
                #pragma unroll
                for (int r = 0; r < 4; ++r) {
                    float v = accm[mt_i][r] + bb;
                    v = v * 0.5f * (1.f + erff(v * 0.70710678118654752f));
                    xb[mt_i * 16 + (l >> 4) * 4 + r][colw] = f2bu(v);
                }
        }
        __syncthreads();
        s16x8 am[4][4];
        #pragma unroll
        for (int mt_i = 0; mt_i < 4; ++mt_i)
            #pragma unroll
            for (int kt = 0; kt < 4; ++kt)
                am[mt_i][kt] = *(const s16x8*)&xb[mt_i * 16 + (l & 15)][kt * 32 + (l >> 4) * 8];
        #pragma unroll
        for (int nt = 0; nt < 2; ++nt) {
            int colo = w * 32 + nt * 16 + (l & 15);
            s16x8 bw[4];
            #pragma unroll
            for (int kt = 0; kt < 4; ++kt) {
                int k0 = cc * 128 + kt * 32 + (l >> 4) * 8;
                #pragma unroll
                for (int j = 0; j < 8; ++j)
                    bw[kt][j] = (short)f2bu(Wf2[(size_t)(k0 + j) * H + colo]);
            }
            #pragma unroll
            for (int kt = 0; kt < 4; ++kt)
                #pragma unroll
                for (int mt_i = 0; mt_i < 4; ++mt_i)
                    acc2[mt_i][nt] = __builtin_amdgcn_mfma_f32_16x16x32_bf16(am[mt_i][kt], bw[kt], acc2[mt_i][nt], 0, 0, 0);
        }
        __syncthreads();
    }

    #pragma unroll
    for (int nt = 0; nt < 2; ++nt) {
        int col = w * 32 + nt * 16 + (l & 15);
        float bb = bf2[col];
        #pragma unroll
        for (int mt_i = 0; mt_i < 4; ++mt_i)
            #pragma unroll
            for (int r = 0; r < 4; ++r) {
                int row = mt_i * 16 + (l >> 4) * 4 + r;
                size_t gg = (size_t)(g0 + row) * H + col;
                htok[gg] += acc2[mt_i][nt][r] + bb;
            }
    }
}

__global__ __launch_bounds__(128) void k_nodeemb(const float* __restrict__ htok,
                                                 const float* __restrict__ og,
                                                 const float* __restrict__ ob,
                                                 float* __restrict__ nemb) {
    int n = blockIdx.x, c = threadIdx.x;
    const float* hr = htok + (size_t)n * 4 * H;
    float v = 0.25f * (hr[c] + hr[H + c] + hr[2 * H + c] + hr[3 * H + c]);
    float s = v, ss = v * v;
    #pragma unroll
    for (int m = 1; m < 64; m <<= 1) { s += __shfl_xor(s, m); ss += __shfl_xor(ss, m); }
    __shared__ float red[4];
    if ((threadIdx.x & 63) == 0) {
        red[(threadIdx.x >> 6) * 2] = s;
        red[(threadIdx.x >> 6) * 2 + 1] = ss;
    }
    __syncthreads();
    s = red[0] + red[2];
    ss = red[1] + red[3];
    float mu = s * (1.f / 128.f);
    float var = ss * (1.f / 128.f) - mu * mu;
    float inv = rsqrtf(var + 1e-5f);
    nemb[(size_t)n * H + c] = (v - mu) * inv * og[c] + ob[c];
}

__global__ __launch_bounds__(128) void k_out(const float* __restrict__ nemb,
                                             float* __restrict__ out) {
    int g = blockIdx.x, c = threadIdx.x;
    float acc = 0.f;
    for (int i = 0; i < 128; ++i) acc += nemb[(size_t)(g * 128 + i) * H + c];
    out[g * H + c] = acc;
}

// ------------------------------------------------------------- launch ----

extern "C" void kernel_launch(void* const* d_in, const int* in_sizes, int n_in,
                              void* d_out, int out_size, void* d_ws, size_t ws_size,
                              hipStream_t stream) {
    (void)in_sizes; (void)n_in; (void)out_size;
    const int* edge_index    = (const int*)d_in[0];
    const int* intra_ei      = (const int*)d_in[1];
    const int* edge_attr_ids = (const int*)d_in[2];
    const int* intra_ea_ids  = (const int*)d_in[3];
    const int* node_ids      = (const int*)d_in[4];
    const int* x_ids         = (const int*)d_in[5];
    const float* log_probs   = (const float*)d_in[7];
    const float* atom_emb    = (const float*)d_in[8];
    const float* bond_emb    = (const float*)d_in[9];
    const float* rwse_W      = (const float*)d_in[10];
    const float* rwse_b      = (const float*)d_in[11];
    const float* gnn_W1      = (const float*)d_in[12];
    const float* gnn_b1      = (const float*)d_in[13];
    const float* gnn_W2      = (const float*)d_in[14];
    const float* gnn_b2      = (const float*)d_in[15];
    const float* ro_ln1_g    = (const float*)d_in[16];
    const float* ro_ln1_b    = (const float*)d_in[17];
    const float* ro_Wqkv     = (const float*)d_in[18];
    const float* ro_bqkv     = (const float*)d_in[19];
    const float* ro_Wo       = (const float*)d_in[20];
    const float* ro_bo       = (const float*)d_in[21];
    const float* ro_ln2_g    = (const float*)d_in[22];
    const float* ro_ln2_b    = (const float*)d_in[23];
    const float* ro_Wf1      = (const float*)d_in[24];
    const float* ro_bf1      = (const float*)d_in[25];
    const float* ro_Wf2      = (const float*)d_in[26];
    const float* ro_bf2      = (const float*)d_in[27];
    const float* out_ln_g    = (const float*)d_in[28];
    const float* out_ln_b    = (const float*)d_in[29];
    const float* ht_alpha    = (const float*)d_in[30];

    char* ws = (char*)d_ws;
    size_t off = 0;
    auto alloc = [&](size_t nbytes) {
        char* p = ws + off;
        off += (nbytes + 255) & ~(size_t)255;
        return p;
    };
    float* T       = (float*)alloc((size_t)B_GRAPHS * 128 * 128 * 4);
    float* rwse    = (float*)alloc((size_t)N_TOTAL * STEPS * 4);
    float* base    = (float*)alloc((size_t)N_TOTAL * H * 4);
    float* gbuf    = (float*)alloc((size_t)2 * N_TOTAL * H * 4);
    float* htok    = (float*)alloc((size_t)S_SUB * H * 4);
    float* nemb    = (float*)alloc((size_t)N_TOTAL * H * 4);
    bf16*  z       = (bf16*)alloc((size_t)FLATN * H * 2);
    bf16*  h       = (bf16*)alloc((size_t)FLATN * H * 2);
    int*   deg     = (int*)alloc((size_t)FLATN * 4);
    int*   rp      = (int*)alloc((size_t)FLATN * 4);
    int*   cursor  = (int*)alloc((size_t)FLATN * 4);
    int*   payload = (int*)alloc((size_t)E_INTRA * 4);
    int*   degN    = (int*)alloc((size_t)N_TOTAL * 4);
    int*   rpN     = (int*)alloc((size_t)N_TOTAL * 4);
    int*   cursorN = (int*)alloc((size_t)N_TOTAL * 4);
    int*   poolidx = (int*)alloc((size_t)FLATN * 4);
    int*   bsum    = (int*)alloc(1024 * 4);
    int*   bsumN   = (int*)alloc(16 * 4);
    float* gpool   = gbuf;
    float* gagg    = gbuf + (size_t)N_TOTAL * H;

    if (off > ws_size) return;

    // ---- CSR build ----
    k_zeroi<<<FLATN / 256, 256, 0, stream>>>(deg, FLATN);
    k_zeroi<<<N_TOTAL / 256, 256, 0, stream>>>(degN, N_TOTAL);
    k_hist_edge<<<E_INTRA / 256, 256, 0, stream>>>(intra_ei, deg);
    k_hist_pool<<<FLATN / 256, 256, 0, stream>>>(node_ids, degN);
    k_scan_blk<<<FLATN / 256, 256, 0, stream>>>(deg, rp, bsum, FLATN);
    k_scan_top<<<1, 256, 0, stream>>>(bsum, FLATN / 256);
    k_scan_add<<<FLATN / 256, 256, 0, stream>>>(rp, bsum, cursor, FLATN);
    k_scan_blk<<<N_TOTAL / 256, 256, 0, stream>>>(degN, rpN, bsumN, N_TOTAL);
    k_scan_top<<<1, 256, 0, stream>>>(bsumN, N_TOTAL / 256);
    k_scan_add<<<N_TOTAL / 256, 256, 0, stream>>>(rpN, bsumN, cursorN, N_TOTAL);
    k_scatter_edge<<<E_INTRA / 256, 256, 0, stream>>>(intra_ei, intra_ea_ids, cursor, payload);
    k_scatter_pool<<<FLATN / 256, 256, 0, stream>>>(node_ids, cursorN, poolidx);

    // ---- RWSE ----
    k_zero4<<<(B_GRAPHS * 128 * 128 / 4 + 255) / 256, 256, 0, stream>>>((float4*)T, B_GRAPHS * 128 * 128 / 4);
    k_adj<<<E_GLOB / 256, 256, 0, stream>>>(edge_index, T);
    k_rownorm<<<(B_GRAPHS * 128) / 4, 256, 0, stream>>>(T);
    k_rwse_mfma<<<B_GRAPHS * RWG, 256, 0, stream>>>(T, rwse);
    k_rwse_head<<<(N_TOTAL * H) / 256, 256, 0, stream>>>(rwse, rwse_W, rwse_b, atom_emb, x_ids, base);
    k_hinit<<<(FLATN * H) / 256, 256, 0, stream>>>(base, node_ids, h);

    // ---- GNN layers ----
    for (int l = 0; l < L_GNN; ++l) {
        k_pool_csr<<<(N_TOTAL * H) / 256, 256, 0, stream>>>(h, rpN, degN, poolidx, gpool, gagg);
        k_gagg<<<(E_GLOB * H) / 256, 256, 0, stream>>>(gpool, bond_emb, edge_index, edge_attr_ids, gagg);
        k_aggz<<<(FLATN * 16) / 256, 256, 0, stream>>>(h, gagg, bond_emb, node_ids, rp, deg, payload, z);
        k_mlp_fused<<<FLATN / 128, 256, 0, stream>>>(
            gnn_W1 + (size_t)l * H * H, gnn_b1 + l * H,
            gnn_W2 + (size_t)l * H * H, gnn_b2 + l * H,
            z, node_ids, h);
    }

    // ---- Readout ----
    k_tok<<<(S_SUB * H) / 256, 256, 0, stream>>>(h, htok);
    for (int l = 0; l < L_RO; ++l) {
        k_ro_attn<<<S_SUB * M_TOK / 64 / 4, 256, 0, stream>>>(htok,
            ro_ln1_g + l * H, ro_ln1_b + l * H,
            ro_Wqkv + (size_t)l * H * 3 * H, ro_bqkv + l * 3 * H,
            ro_Wo + (size_t)l * H * H, ro_bo + l * H,
            log_probs, ht_alpha);
        k_ro_ffn<<<S_SUB * M_TOK / 64 / 4, 256, 0, stream>>>(htok,
            ro_ln2_g + l * H, ro_ln2_b + l * H,
            ro_Wf1 + (size_t)l * H * FFN, ro_bf1 + l * FFN,
            ro_Wf2 + (size_t)l * FFN * H, ro_bf2 + l * H);
    }
    k_nodeemb<<<N_TOTAL, 128, 0, stream>>>(htok, out_ln_g, out_ln_b, nemb);
    k_out<<<B_GRAPHS, 128, 0, stream>>>(nemb, (float*)d_out);
}